// Round 14
// baseline (260.491 us; speedup 1.0000x reference)
//
#include <hip/hip_runtime.h>
#include <cstdint>
#include <cstddef>

constexpr int CIN  = 16;
constexpr int COUT = 64;
constexpr int NMOM = 16 + 136;          // 16 sums + 136 upper-tri products
constexpr double BN_EPS = 1e-3;

typedef float v2f __attribute__((ext_vector_type(2)));
typedef __fp16 v2h __attribute__((ext_vector_type(2)));   // matches cvt_pkrtz/fdot2 builtin type
constexpr float INV_2PI = 0.15915494309189535f;

// prep layout (floats): A[64], B[64], c[64], Wc[16*64]
constexpr int P_A = 0, P_B = 64, P_C = 128, P_WC = 192, P_SZ = 192 + CIN * COUT;

constexpr int CHUNK = 512;              // scan chunk
constexpr int MB = 512;                 // moments blocks per input; 1 partial row/block

__device__ __forceinline__ unsigned bc_u(v2h h) { return __builtin_bit_cast(unsigned, h); }
__device__ __forceinline__ v2h bc_h(unsigned u) { return __builtin_bit_cast(v2h, u); }

// ---------------- moments + histogram (one launch) -------------------------
__global__ __launch_bounds__(256) void moments2_kernel(const float* __restrict__ xyz, int n1,
                                                       const float* __restrict__ feat, int n2,
                                                       const int* __restrict__ unq,
                                                       int* __restrict__ cnt,
                                                       float* __restrict__ partP,
                                                       float* __restrict__ partF)
{
    const int bb  = blockIdx.x;
    const bool second = (bb >= MB);
    const float* x = second ? feat : xyz;
    const int    n = second ? n2 : n1;
    float* part    = second ? partF : partP;
    const int blk  = second ? bb - MB : bb;

    float acc[NMOM];
#pragma unroll
    for (int i = 0; i < NMOM; i++) acc[i] = 0.f;

    int tid = blk * 256 + threadIdx.x;
    int stride = MB * 256;
    for (int r = tid; r < n; r += stride) {
        const float4* xp = (const float4*)(x + (size_t)r * CIN);
        float4 a0 = xp[0], a1 = xp[1], a2 = xp[2], a3 = xp[3];
        if (!second) atomicAdd(cnt + unq[r], 1);     // fused histogram
        float v[16] = {a0.x,a0.y,a0.z,a0.w, a1.x,a1.y,a1.z,a1.w,
                       a2.x,a2.y,a2.z,a2.w, a3.x,a3.y,a3.z,a3.w};
#pragma unroll
        for (int i = 0; i < 16; i++) acc[i] += v[i];
        int c = 16;
#pragma unroll
        for (int k = 0; k < 16; k++)
#pragma unroll
            for (int l = k; l < 16; l++) { acc[c] = fmaf(v[k], v[l], acc[c]); c++; }
    }

    const int lane = threadIdx.x & 63;
    const int wid  = threadIdx.x >> 6;
    float r0 = 0.f, r1 = 0.f, r2 = 0.f;
#pragma unroll
    for (int i = 0; i < NMOM; i++) {
        float s = acc[i];
#pragma unroll
        for (int off = 1; off < 64; off <<= 1) s += __shfl_xor(s, off, 64);
        if (i < 64)       { if (lane == i)       r0 = s; }
        else if (i < 128) { if (lane == i - 64)  r1 = s; }
        else              { if (lane == i - 128) r2 = s; }
    }

    __shared__ float red[4][NMOM];
    red[wid][lane] = r0;
    red[wid][64 + lane] = r1;
    if (lane < NMOM - 128) red[wid][128 + lane] = r2;
    __syncthreads();
    int t = threadIdx.x;
    if (t < NMOM) {
        float s = red[0][t] + red[1][t] + red[2][t] + red[3][t];
        part[(size_t)blk * NMOM + t] = s;
    }
}

// ---------------- prep: fold BN analytically into the linears --------------
__global__ __launch_bounds__(256) void prep_kernel(const float* __restrict__ Wpre, const float* __restrict__ bpre,
                            const float* __restrict__ gpre, const float* __restrict__ bepre,
                            const float* __restrict__ Wpos, const float* __restrict__ bpos,
                            const float* __restrict__ partP, const float* __restrict__ partF,
                            int nrows, int Np, int Vv,
                            float* __restrict__ prepP, float* __restrict__ prepF)
{
    const int t  = threadIdx.x;   // 0..255
    const int br = blockIdx.x;    // 0 or 1
    const float* part = br ? partF : partP;
    const double n    = br ? (double)Vv : (double)Np;
    const double inv_n = 1.0 / n;
    float* prep       = br ? prepF : prepP;

    __shared__ float sWpre[CIN * 64];    // 16x64
    __shared__ float sWpos[64 * 64];     // 64x64
    __shared__ double mom[NMOM];
    __shared__ double sS[64], sB[64];

    for (int i = t; i < CIN * 64; i += 256) sWpre[i] = Wpre[i];
    for (int i = t; i < 64 * 64; i += 256)  sWpos[i] = Wpos[i];

    if (t < NMOM) {
        double s0 = 0, s1 = 0, s2 = 0, s3 = 0, s4 = 0, s5 = 0, s6 = 0, s7 = 0;
        int r = 0;
        for (; r + 8 <= nrows; r += 8) {
            s0 += (double)part[(size_t)(r + 0) * NMOM + t];
            s1 += (double)part[(size_t)(r + 1) * NMOM + t];
            s2 += (double)part[(size_t)(r + 2) * NMOM + t];
            s3 += (double)part[(size_t)(r + 3) * NMOM + t];
            s4 += (double)part[(size_t)(r + 4) * NMOM + t];
            s5 += (double)part[(size_t)(r + 5) * NMOM + t];
            s6 += (double)part[(size_t)(r + 6) * NMOM + t];
            s7 += (double)part[(size_t)(r + 7) * NMOM + t];
        }
        for (; r < nrows; r++) s0 += (double)part[(size_t)r * NMOM + t];
        mom[t] = ((s0 + s1) + (s2 + s3)) + ((s4 + s5) + (s6 + s7));
    }
    __syncthreads();

    if (t < 64) {
        const int k = t;
        double mu[16];
#pragma unroll
        for (int i = 0; i < 16; i++) mu[i] = mom[i] * inv_n;
        double w[16];
#pragma unroll
        for (int i = 0; i < 16; i++) w[i] = (double)sWpre[i * 64 + k];

        double mk = (double)bpre[k];
#pragma unroll
        for (int i = 0; i < 16; i++) mk += mu[i] * w[i];

        double var = 0.0;
        int c = 16;
#pragma unroll
        for (int a = 0; a < 16; a++)
#pragma unroll
            for (int l = a; l < 16; l++) {
                double cov = mom[c] * inv_n - mu[a] * mu[l]; c++;
                var += (a == l ? 1.0 : 2.0) * w[a] * w[l] * cov;
            }

        double s_k = (double)gpre[k] / sqrt(var + BN_EPS);
        double B_k = (double)bepre[k] + s_k * ((double)bpre[k] - mk);
        sS[k] = s_k; sB[k] = B_k;
    }
    __syncthreads();

    if (t < 64) {
        const int k = t;
        double c0 = (double)bpos[k], c1 = 0.0;
        for (int j = 0; j < 64; j += 2) {
            c0 += sB[j]     * (double)sWpos[j * 64 + k];
            c1 += sB[j + 1] * (double)sWpos[(j + 1) * 64 + k];
        }
        prep[P_A + k] = (float)sS[k];
        prep[P_B + k] = (float)sB[k];
        prep[P_C + k] = (float)(c0 + c1);
    }

    {
        const int k  = t & 63;
        const int i0 = t >> 6;
        for (int i = i0; i < 16; i += 4) {
            double w0 = 0.0, w1 = 0.0;
            for (int j = 0; j < 64; j += 2) {
                w0 += (double)sWpre[i * 64 + j]     * sS[j]     * (double)sWpos[j * 64 + k];
                w1 += (double)sWpre[i * 64 + j + 1] * sS[j + 1] * (double)sWpos[(j + 1) * 64 + k];
            }
            prep[P_WC + i * 64 + k] = (float)(w0 + w1);
        }
    }
}

// ---------------- scan stage a: per-chunk sums ------------------------------
__global__ __launch_bounds__(256) void scan_a(const int* __restrict__ cnt, int V,
                                              int* __restrict__ chunkSum)
{
    const int b = blockIdx.x, t = threadIdx.x;
    int base = b * CHUNK;
    int i0 = base + t * 2, i1 = i0 + 1;
    int s = ((i0 < V) ? cnt[i0] : 0) + ((i1 < V) ? cnt[i1] : 0);
    __shared__ int red[4];
    const int lane = t & 63, wid = t >> 6;
#pragma unroll
    for (int off = 1; off < 64; off <<= 1) s += __shfl_xor(s, off, 64);
    if (lane == 0) red[wid] = s;
    __syncthreads();
    if (t == 0) chunkSum[b] = red[0] + red[1] + red[2] + red[3];
}

// ---------------- scan stage b: exclusive scan of chunk sums (<=256) --------
__global__ __launch_bounds__(256) void scan_b(const int* __restrict__ chunkSum, int nch,
                                              int* __restrict__ chunkBase,
                                              int* __restrict__ start, int V, int N)
{
    const int t = threadIdx.x;
    __shared__ int a[256];
    int v = (t < nch) ? chunkSum[t] : 0;
    a[t] = v;
    __syncthreads();
    for (int off = 1; off < 256; off <<= 1) {
        int add = (t >= off) ? a[t - off] : 0;
        __syncthreads();
        a[t] += add;
        __syncthreads();
    }
    chunkBase[t] = a[t] - v;   // exclusive
    if (t == 0) start[V] = N;
}

// ---------------- scan stage c: per-chunk exclusive scan -> start ----------
__global__ __launch_bounds__(64) void scan_c(const int* __restrict__ cnt, int V,
                                             const int* __restrict__ chunkBase,
                                             int* __restrict__ start)
{
    const int b = blockIdx.x;
    const int lane = threadIdx.x;
    const int base = b * CHUNK + lane * 8;
    int e[8];
    int run = 0;
#pragma unroll
    for (int j = 0; j < 8; j++) {
        int idx = base + j;
        int c = (idx < V) ? cnt[idx] : 0;
        e[j] = run;
        run += c;
    }
    int incl = run;
#pragma unroll
    for (int off = 1; off < 64; off <<= 1) {
        int vv = __shfl_up(incl, off, 64);
        if (lane >= off) incl += vv;
    }
    int excl = incl - run;
    int myBase = chunkBase[b] + excl;
#pragma unroll
    for (int j = 0; j < 8; j++) {
        int idx = base + j;
        if (idx < V) start[idx] = myBase + e[j];
    }
}

// ---------------- scatter: point indices into voxel-sorted order -----------
__global__ __launch_bounds__(256) void scatter_kernel(const int* __restrict__ unq, int N,
                                                      const int* __restrict__ start,
                                                      int* __restrict__ cursor,
                                                      int* __restrict__ sortedIdx)
{
    int t = blockIdx.x * blockDim.x + threadIdx.x;
    int stride = gridDim.x * blockDim.x;
    for (; t < N; t += stride) {
        int v = unq[t];
        int pos = start[v] + atomicAdd(cursor + v, 1);
        sortedIdx[pos] = t;
    }
}

// ---------------- fused voxel pass: f16 LDS rows + v_dot2_f32_f16 ----------
// Rows staged in LDS as f16 (32 B/row): per-point reads drop from 4x to
// 2x ds_read_b128 (the measured LDS-throughput floor). Dots via fdot2.
__global__ __launch_bounds__(256) void fused_pass(const float* __restrict__ xyz,
                                                  const float* __restrict__ feat,
                                                  const int* __restrict__ sortedIdx,
                                                  const int* __restrict__ start,
                                                  const float* __restrict__ Wpre,
                                                  const float* __restrict__ prepP,
                                                  const float* __restrict__ prepF,
                                                  float* __restrict__ outFinal,
                                                  float* __restrict__ statsPart, int V)
{
    const int lane = threadIdx.x & 63;
    const int wid  = threadIdx.x >> 6;
    const int rq   = lane >> 2;      // row slot 0..15
    const int cc   = lane & 3;       // quarter within row

    // per-wave LDS: 3 buffers x 16 rows x 16 halfs (512 B each)
    __shared__ uint2 ldsq[4][3][64];
    __shared__ unsigned sWcF2[8 * 64];      // center dw weights, half2-packed
    uint2* bufA = ldsq[wid][0];
    uint2* bufB = ldsq[wid][1];
    uint2* remb = ldsq[wid][2];
    const int wslot = rq * 4 + cc;

    for (int i = threadIdx.x; i < 8 * 64; i += 256) {
        int fi = i >> 6, ch = i & 63;
        sWcF2[i] = bc_u(__builtin_amdgcn_cvt_pkrtz(prepF[P_WC + (2 * fi) * 64 + ch],
                                                   prepF[P_WC + (2 * fi + 1) * 64 + ch]));
    }
    __syncthreads();

    v2h wpre2[8], wcp2[8];
#pragma unroll
    for (int i = 0; i < 8; i++) {
        wpre2[i] = __builtin_amdgcn_cvt_pkrtz(Wpre[(2 * i) * 64 + lane],
                                              Wpre[(2 * i + 1) * 64 + lane]);
        wcp2[i]  = __builtin_amdgcn_cvt_pkrtz(prepP[P_WC + (2 * i) * 64 + lane],
                                              prepP[P_WC + (2 * i + 1) * 64 + lane]);
    }

    const float AP = prepP[P_A + lane], BP = prepP[P_B + lane];
    const float CPr = prepP[P_C + lane] * INV_2PI;
    const float AF = prepF[P_A + lane], BF = prepF[P_B + lane];
    const float CFr = prepF[P_C + lane] * INV_2PI;

    const int wave = __builtin_amdgcn_readfirstlane((int)((blockIdx.x * blockDim.x + threadIdx.x) >> 6));
    const int nw   = (gridDim.x * blockDim.x) >> 6;
    float s1 = 0.f, s2 = 0.f;

    auto prefetch = [&](int v, int& sb, int& m, uint2& u) {
        sb = __builtin_amdgcn_readfirstlane(start[v]);
        int se = __builtin_amdgcn_readfirstlane(start[v + 1]);
        m = se - sb;
        int ms0 = min(m, 15);
        int row = min(rq, ms0);
        int ridx = sortedIdx[sb + row];        // padded; value unused when row==ms0
        const float* bp = (row == ms0) ? (feat + (size_t)v * CIN)
                                       : (xyz  + (size_t)ridx * CIN);
        float4 q = *(const float4*)(bp + cc * 4);
        u.x = bc_u(__builtin_amdgcn_cvt_pkrtz(q.x, q.y));
        u.y = bc_u(__builtin_amdgcn_cvt_pkrtz(q.z, q.w));
    };

    auto pointmath = [&](const uint2* buf, int j, v2f& acc) {
        uint4 a = ((const uint4*)buf)[j * 2 + 0];   // uniform -> broadcast
        uint4 b = ((const uint4*)buf)[j * 2 + 1];
        v2h xs[8] = {bc_h(a.x), bc_h(a.y), bc_h(a.z), bc_h(a.w),
                     bc_h(b.x), bc_h(b.y), bc_h(b.z), bc_h(b.w)};
        float dx = 0.f, dw = 0.f;
#pragma unroll
        for (int i = 0; i < 8; i++) {
            dx = __builtin_amdgcn_fdot2(xs[i], wpre2[i], dx, false);
            dw = __builtin_amdgcn_fdot2(xs[i], wcp2[i],  dw, false);
        }
        float p  = fmaf(AP, dx, BP);
        float r  = fmaf(dw, INV_2PI, CPr);
        float sv = __builtin_amdgcn_sinf(r);
        float cv = __builtin_amdgcn_cosf(r);
        acc += p * (v2f){sv, cv};
    };

    int v = wave;
    int sb = 0, m = 0;
    uint2* cur = bufA;
    uint2* nxt = bufB;
    if (v < V) {
        uint2 u; prefetch(v, sb, m, u);
        cur[wslot] = u;                        // ds_write_b64
    }

    while (v < V) {
        const int vn = v + nw;
        int sbn = 0, mn = 0; uint2 un = {};
        if (vn < V) prefetch(vn, sbn, mn, un); // VMEM in flight during compute

        const int ms0 = min(m, 15);
        v2f acc = (v2f){0.f, 0.f};

        for (int j = 0; j < ms0; j++) pointmath(cur, j, acc);

        // remainder rows for big voxels (m > 15), rare
        for (int base = 15; base < m; base += 16) {
            const int msr  = min(16, m - base);
            const int rowc = min(rq, msr - 1);
            int ridx = sortedIdx[sb + base + rowc];
            float4 q = *(const float4*)(xyz + (size_t)ridx * CIN + cc * 4);
            uint2 u;
            u.x = bc_u(__builtin_amdgcn_cvt_pkrtz(q.x, q.y));
            u.y = bc_u(__builtin_amdgcn_cvt_pkrtz(q.z, q.w));
            remb[wslot] = u;
            for (int j = 0; j < msr; j++) pointmath(remb, j, acc);
        }

        // center row (slot ms0): dx with wpre2, dw with sWcF2 (per-lane)
        {
            uint4 a = ((const uint4*)cur)[ms0 * 2 + 0];
            uint4 b = ((const uint4*)cur)[ms0 * 2 + 1];
            v2h xs[8] = {bc_h(a.x), bc_h(a.y), bc_h(a.z), bc_h(a.w),
                         bc_h(b.x), bc_h(b.y), bc_h(b.z), bc_h(b.w)};
            float dx = 0.f, dw = 0.f;
#pragma unroll
            for (int i = 0; i < 8; i++) {
                dx = __builtin_amdgcn_fdot2(xs[i], wpre2[i], dx, false);
                dw = __builtin_amdgcn_fdot2(xs[i], bc_h(sWcF2[i * 64 + lane]), dw, false);
            }
            float f  = fmaf(AF, dx, BF);
            float r  = fmaf(dw, INV_2PI, CFr);
            float sv = __builtin_amdgcn_sinf(r);
            float cv = __builtin_amdgcn_cosf(r);
            float cs = f * sv, ccn = f * cv;
            float fin = fmaf(acc.x + cs, cs, (acc.y + ccn) * ccn);
            outFinal[(size_t)v * 64 + lane] = fin;
            s1 += fin;
            s2 = fmaf(fin, fin, s2);
        }

        if (vn < V) nxt[wslot] = un;           // stage next voxel
        uint2* tmp = cur; cur = nxt; nxt = tmp;
        v = vn; sb = sbn; m = mn;
    }

    __shared__ float sh1[4][64], sh2[4][64];
    sh1[wid][lane] = s1; sh2[wid][lane] = s2;
    __syncthreads();
    if (threadIdx.x < 64) {
        float t1 = sh1[0][lane] + sh1[1][lane] + sh1[2][lane] + sh1[3][lane];
        float t2 = sh2[0][lane] + sh2[1][lane] + sh2[2][lane] + sh2[3][lane];
        float* row = statsPart + (size_t)(blockIdx.x & 63) * 128;
        atomicAdd(row + lane, t1);
        atomicAdd(row + 64 + lane, t2);
    }
}

// ---------------- normalize + relu, stats reduced per-block ----------------
__global__ __launch_bounds__(256) void norm_kernel(float* __restrict__ out,
                                                   const float* __restrict__ sp,
                                                   const float* __restrict__ gn,
                                                   const float* __restrict__ bnb,
                                                   int V, size_t n4)
{
    __shared__ float sNs[64], sNb[64];
    const int t = threadIdx.x;
    if (t < 64) {
        double u1 = 0.0, u2 = 0.0;
#pragma unroll 4
        for (int r = 0; r < 64; r++) {
            u1 += (double)sp[(size_t)r * 128 + t];
            u2 += (double)sp[(size_t)r * 128 + 64 + t];
        }
        double mean = u1 / (double)V;
        double var  = u2 / (double)V - mean * mean;
        double ns   = (double)gn[t] / sqrt(var + BN_EPS);
        sNs[t] = (float)ns;
        sNb[t] = (float)((double)bnb[t] - ns * mean);
    }
    __syncthreads();

    const float4* ns4 = (const float4*)sNs;
    const float4* nb4 = (const float4*)sNb;
    float4* o4 = (float4*)out;
    size_t i = (size_t)blockIdx.x * blockDim.x + threadIdx.x;
    size_t stride = (size_t)gridDim.x * blockDim.x;
    for (; i < n4; i += stride) {
        int g = (int)(i & 15);
        float4 sc = ns4[g], bi = nb4[g];
        float4 w = o4[i];
        w.x = fmaxf(0.f, fmaf(sc.x, w.x, bi.x));
        w.y = fmaxf(0.f, fmaf(sc.y, w.y, bi.y));
        w.z = fmaxf(0.f, fmaf(sc.z, w.z, bi.z));
        w.w = fmaxf(0.f, fmaf(sc.w, w.w, bi.w));
        o4[i] = w;
    }
}

extern "C" void kernel_launch(void* const* d_in, const int* in_sizes, int n_in,
                              void* d_out, int out_size, void* d_ws, size_t ws_size,
                              hipStream_t stream)
{
    const float* feat  = (const float*)d_in[0];
    const float* xyz   = (const float*)d_in[1];
    const int*   unq   = (const int*)d_in[2];
    const float* Wpre  = (const float*)d_in[3];
    const float* bpre  = (const float*)d_in[4];
    const float* gpre  = (const float*)d_in[5];
    const float* bepre = (const float*)d_in[6];
    const float* Wpos  = (const float*)d_in[7];
    const float* bpos  = (const float*)d_in[8];
    const float* gn    = (const float*)d_in[9];
    const float* bnb   = (const float*)d_in[10];

    const int V = in_sizes[0] / CIN;
    const int N = in_sizes[1] / CIN;
    const int nch = (V + CHUNK - 1) / CHUNK;

    char* ws = (char*)d_ws;
    size_t off = 0;
    auto alloc = [&](size_t bytes) { void* p = ws + off; off += (bytes + 255) & ~size_t(255); return p; };

    // zeroed region first: cnt, cursor, statsPart (one memset)
    int*   cnt       = (int*)alloc((size_t)V * 4);
    int*   cursor    = (int*)alloc((size_t)V * 4);
    float* statsPart = (float*)alloc(64 * 128 * 4);
    const size_t zeroBytes = off;

    int*   start     = (int*)alloc((size_t)(V + 1) * 4);
    int*   chunkSum  = (int*)alloc(256 * 4);
    int*   chunkBase = (int*)alloc(256 * 4);
    int*   sortedIdx = (int*)alloc((size_t)(N + 64) * 4);  // +64 pad for clamped gather

    float* partP = (float*)alloc((size_t)MB * NMOM * 4);
    float* partF = (float*)alloc((size_t)MB * NMOM * 4);
    float* prepP = (float*)alloc(P_SZ * 4);
    float* prepF = (float*)alloc(P_SZ * 4);

    hipMemsetAsync(d_ws, 0, zeroBytes, stream);

    moments2_kernel<<<2 * MB, 256, 0, stream>>>(xyz, N, feat, V, unq, cnt, partP, partF);
    scan_a<<<nch, 256, 0, stream>>>(cnt, V, chunkSum);
    scan_b<<<1, 256, 0, stream>>>(chunkSum, nch, chunkBase, start, V, N);
    scan_c<<<nch, 64, 0, stream>>>(cnt, V, chunkBase, start);
    scatter_kernel<<<1024, 256, 0, stream>>>(unq, N, start, cursor, sortedIdx);
    prep_kernel<<<2, 256, 0, stream>>>(Wpre, bpre, gpre, bepre, Wpos, bpos,
                                       partP, partF, MB, N, V, prepP, prepF);
    fused_pass<<<2048, 256, 0, stream>>>(xyz, feat, sortedIdx, start, Wpre,
                                         prepP, prepF, (float*)d_out, statsPart, V);
    norm_kernel<<<512, 256, 0, stream>>>((float*)d_out, statsPart, gn, bnb, V,
                                         (size_t)out_size / 4);
}

// Round 15
// 243.106 us; speedup vs baseline: 1.0715x; 1.0715x over previous
//
#include <hip/hip_runtime.h>
#include <cstdint>
#include <cstddef>

constexpr int CIN  = 16;
constexpr int COUT = 64;
constexpr int NMOM = 16 + 136;          // 16 sums + 136 upper-tri products
constexpr double BN_EPS = 1e-3;

typedef float v2f __attribute__((ext_vector_type(2)));
typedef __fp16 v2h __attribute__((ext_vector_type(2)));   // matches cvt_pkrtz/fdot2 builtin type
constexpr float INV_2PI = 0.15915494309189535f;

// prep layout (floats): A[64], B[64], c[64], Wc[16*64]
constexpr int P_A = 0, P_B = 64, P_C = 128, P_WC = 192, P_SZ = 192 + CIN * COUT;

constexpr int CHUNK = 512;              // scan chunk
constexpr int MB = 256;                 // moments blocks per input; 1 partial row/block

__device__ __forceinline__ unsigned bc_u(v2h h) { return __builtin_bit_cast(unsigned, h); }
__device__ __forceinline__ v2h bc_h(unsigned u) { return __builtin_bit_cast(v2h, u); }

// ---------------- moments + histogram (one launch) -------------------------
// __launch_bounds__(256, 1): acc[NMOM]=152 floats/thread needs ~200 VGPR;
// default heuristic capped at 96 -> scratch spill (31.8 MB of spill writes,
// 88 us). min-1-wave/EU lifts the cap to 512.
__global__ __launch_bounds__(256, 1) void moments2_kernel(const float* __restrict__ xyz, int n1,
                                                       const float* __restrict__ feat, int n2,
                                                       const int* __restrict__ unq,
                                                       int* __restrict__ cnt,
                                                       float* __restrict__ partP,
                                                       float* __restrict__ partF)
{
    const int bb  = blockIdx.x;
    const bool second = (bb >= MB);
    const float* x = second ? feat : xyz;
    const int    n = second ? n2 : n1;
    float* part    = second ? partF : partP;
    const int blk  = second ? bb - MB : bb;

    float acc[NMOM];
#pragma unroll
    for (int i = 0; i < NMOM; i++) acc[i] = 0.f;

    int tid = blk * 256 + threadIdx.x;
    int stride = MB * 256;
    for (int r = tid; r < n; r += stride) {
        const float4* xp = (const float4*)(x + (size_t)r * CIN);
        float4 a0 = xp[0], a1 = xp[1], a2 = xp[2], a3 = xp[3];
        if (!second) atomicAdd(cnt + unq[r], 1);     // fused histogram
        float v[16] = {a0.x,a0.y,a0.z,a0.w, a1.x,a1.y,a1.z,a1.w,
                       a2.x,a2.y,a2.z,a2.w, a3.x,a3.y,a3.z,a3.w};
#pragma unroll
        for (int i = 0; i < 16; i++) acc[i] += v[i];
        int c = 16;
#pragma unroll
        for (int k = 0; k < 16; k++)
#pragma unroll
            for (int l = k; l < 16; l++) { acc[c] = fmaf(v[k], v[l], acc[c]); c++; }
    }

    const int lane = threadIdx.x & 63;
    const int wid  = threadIdx.x >> 6;
    float r0 = 0.f, r1 = 0.f, r2 = 0.f;
#pragma unroll
    for (int i = 0; i < NMOM; i++) {
        float s = acc[i];
#pragma unroll
        for (int off = 1; off < 64; off <<= 1) s += __shfl_xor(s, off, 64);
        if (i < 64)       { if (lane == i)       r0 = s; }
        else if (i < 128) { if (lane == i - 64)  r1 = s; }
        else              { if (lane == i - 128) r2 = s; }
    }

    __shared__ float red[4][NMOM];
    red[wid][lane] = r0;
    red[wid][64 + lane] = r1;
    if (lane < NMOM - 128) red[wid][128 + lane] = r2;
    __syncthreads();
    int t = threadIdx.x;
    if (t < NMOM) {
        float s = red[0][t] + red[1][t] + red[2][t] + red[3][t];
        part[(size_t)blk * NMOM + t] = s;
    }
}

// ---------------- prep: fold BN analytically into the linears --------------
__global__ __launch_bounds__(256) void prep_kernel(const float* __restrict__ Wpre, const float* __restrict__ bpre,
                            const float* __restrict__ gpre, const float* __restrict__ bepre,
                            const float* __restrict__ Wpos, const float* __restrict__ bpos,
                            const float* __restrict__ partP, const float* __restrict__ partF,
                            int nrows, int Np, int Vv,
                            float* __restrict__ prepP, float* __restrict__ prepF)
{
    const int t  = threadIdx.x;   // 0..255
    const int br = blockIdx.x;    // 0 or 1
    const float* part = br ? partF : partP;
    const double n    = br ? (double)Vv : (double)Np;
    const double inv_n = 1.0 / n;
    float* prep       = br ? prepF : prepP;

    __shared__ float sWpre[CIN * 64];    // 16x64
    __shared__ float sWpos[64 * 64];     // 64x64
    __shared__ double mom[NMOM];
    __shared__ double sS[64], sB[64];

    for (int i = t; i < CIN * 64; i += 256) sWpre[i] = Wpre[i];
    for (int i = t; i < 64 * 64; i += 256)  sWpos[i] = Wpos[i];

    if (t < NMOM) {
        double s0 = 0, s1 = 0, s2 = 0, s3 = 0, s4 = 0, s5 = 0, s6 = 0, s7 = 0;
        int r = 0;
        for (; r + 8 <= nrows; r += 8) {
            s0 += (double)part[(size_t)(r + 0) * NMOM + t];
            s1 += (double)part[(size_t)(r + 1) * NMOM + t];
            s2 += (double)part[(size_t)(r + 2) * NMOM + t];
            s3 += (double)part[(size_t)(r + 3) * NMOM + t];
            s4 += (double)part[(size_t)(r + 4) * NMOM + t];
            s5 += (double)part[(size_t)(r + 5) * NMOM + t];
            s6 += (double)part[(size_t)(r + 6) * NMOM + t];
            s7 += (double)part[(size_t)(r + 7) * NMOM + t];
        }
        for (; r < nrows; r++) s0 += (double)part[(size_t)r * NMOM + t];
        mom[t] = ((s0 + s1) + (s2 + s3)) + ((s4 + s5) + (s6 + s7));
    }
    __syncthreads();

    if (t < 64) {
        const int k = t;
        double mu[16];
#pragma unroll
        for (int i = 0; i < 16; i++) mu[i] = mom[i] * inv_n;
        double w[16];
#pragma unroll
        for (int i = 0; i < 16; i++) w[i] = (double)sWpre[i * 64 + k];

        double mk = (double)bpre[k];
#pragma unroll
        for (int i = 0; i < 16; i++) mk += mu[i] * w[i];

        double var = 0.0;
        int c = 16;
#pragma unroll
        for (int a = 0; a < 16; a++)
#pragma unroll
            for (int l = a; l < 16; l++) {
                double cov = mom[c] * inv_n - mu[a] * mu[l]; c++;
                var += (a == l ? 1.0 : 2.0) * w[a] * w[l] * cov;
            }

        double s_k = (double)gpre[k] / sqrt(var + BN_EPS);
        double B_k = (double)bepre[k] + s_k * ((double)bpre[k] - mk);
        sS[k] = s_k; sB[k] = B_k;
    }
    __syncthreads();

    if (t < 64) {
        const int k = t;
        double c0 = (double)bpos[k], c1 = 0.0;
        for (int j = 0; j < 64; j += 2) {
            c0 += sB[j]     * (double)sWpos[j * 64 + k];
            c1 += sB[j + 1] * (double)sWpos[(j + 1) * 64 + k];
        }
        prep[P_A + k] = (float)sS[k];
        prep[P_B + k] = (float)sB[k];
        prep[P_C + k] = (float)(c0 + c1);
    }

    {
        const int k  = t & 63;
        const int i0 = t >> 6;
        for (int i = i0; i < 16; i += 4) {
            double w0 = 0.0, w1 = 0.0;
            for (int j = 0; j < 64; j += 2) {
                w0 += (double)sWpre[i * 64 + j]     * sS[j]     * (double)sWpos[j * 64 + k];
                w1 += (double)sWpre[i * 64 + j + 1] * sS[j + 1] * (double)sWpos[(j + 1) * 64 + k];
            }
            prep[P_WC + i * 64 + k] = (float)(w0 + w1);
        }
    }
}

// ---------------- scan stage a: per-chunk sums ------------------------------
__global__ __launch_bounds__(256) void scan_a(const int* __restrict__ cnt, int V,
                                              int* __restrict__ chunkSum)
{
    const int b = blockIdx.x, t = threadIdx.x;
    int base = b * CHUNK;
    int i0 = base + t * 2, i1 = i0 + 1;
    int s = ((i0 < V) ? cnt[i0] : 0) + ((i1 < V) ? cnt[i1] : 0);
    __shared__ int red[4];
    const int lane = t & 63, wid = t >> 6;
#pragma unroll
    for (int off = 1; off < 64; off <<= 1) s += __shfl_xor(s, off, 64);
    if (lane == 0) red[wid] = s;
    __syncthreads();
    if (t == 0) chunkSum[b] = red[0] + red[1] + red[2] + red[3];
}

// ---------------- scan stage b: exclusive scan of chunk sums (<=256) --------
__global__ __launch_bounds__(256) void scan_b(const int* __restrict__ chunkSum, int nch,
                                              int* __restrict__ chunkBase,
                                              int* __restrict__ start, int V, int N)
{
    const int t = threadIdx.x;
    __shared__ int a[256];
    int v = (t < nch) ? chunkSum[t] : 0;
    a[t] = v;
    __syncthreads();
    for (int off = 1; off < 256; off <<= 1) {
        int add = (t >= off) ? a[t - off] : 0;
        __syncthreads();
        a[t] += add;
        __syncthreads();
    }
    chunkBase[t] = a[t] - v;   // exclusive
    if (t == 0) start[V] = N;
}

// ---------------- scan stage c: per-chunk exclusive scan -> start ----------
__global__ __launch_bounds__(64) void scan_c(const int* __restrict__ cnt, int V,
                                             const int* __restrict__ chunkBase,
                                             int* __restrict__ start)
{
    const int b = blockIdx.x;
    const int lane = threadIdx.x;
    const int base = b * CHUNK + lane * 8;
    int e[8];
    int run = 0;
#pragma unroll
    for (int j = 0; j < 8; j++) {
        int idx = base + j;
        int c = (idx < V) ? cnt[idx] : 0;
        e[j] = run;
        run += c;
    }
    int incl = run;
#pragma unroll
    for (int off = 1; off < 64; off <<= 1) {
        int vv = __shfl_up(incl, off, 64);
        if (lane >= off) incl += vv;
    }
    int excl = incl - run;
    int myBase = chunkBase[b] + excl;
#pragma unroll
    for (int j = 0; j < 8; j++) {
        int idx = base + j;
        if (idx < V) start[idx] = myBase + e[j];
    }
}

// ---------------- scatter: point indices into voxel-sorted order -----------
__global__ __launch_bounds__(256) void scatter_kernel(const int* __restrict__ unq, int N,
                                                      const int* __restrict__ start,
                                                      int* __restrict__ cursor,
                                                      int* __restrict__ sortedIdx)
{
    int t = blockIdx.x * blockDim.x + threadIdx.x;
    int stride = gridDim.x * blockDim.x;
    for (; t < N; t += stride) {
        int v = unq[t];
        int pos = start[v] + atomicAdd(cursor + v, 1);
        sortedIdx[pos] = t;
    }
}

// ---------------- fused voxel pass: f16 LDS rows + v_dot2_f32_f16 ----------
__global__ __launch_bounds__(256) void fused_pass(const float* __restrict__ xyz,
                                                  const float* __restrict__ feat,
                                                  const int* __restrict__ sortedIdx,
                                                  const int* __restrict__ start,
                                                  const float* __restrict__ Wpre,
                                                  const float* __restrict__ prepP,
                                                  const float* __restrict__ prepF,
                                                  float* __restrict__ outFinal,
                                                  float* __restrict__ statsPart, int V)
{
    const int lane = threadIdx.x & 63;
    const int wid  = threadIdx.x >> 6;
    const int rq   = lane >> 2;      // row slot 0..15
    const int cc   = lane & 3;       // quarter within row

    // per-wave LDS: 3 buffers x 16 rows x 16 halfs (512 B each)
    __shared__ uint2 ldsq[4][3][64];
    __shared__ unsigned sWcF2[8 * 64];      // center dw weights, half2-packed
    uint2* bufA = ldsq[wid][0];
    uint2* bufB = ldsq[wid][1];
    uint2* remb = ldsq[wid][2];
    const int wslot = rq * 4 + cc;

    for (int i = threadIdx.x; i < 8 * 64; i += 256) {
        int fi = i >> 6, ch = i & 63;
        sWcF2[i] = bc_u(__builtin_amdgcn_cvt_pkrtz(prepF[P_WC + (2 * fi) * 64 + ch],
                                                   prepF[P_WC + (2 * fi + 1) * 64 + ch]));
    }
    __syncthreads();

    v2h wpre2[8], wcp2[8];
#pragma unroll
    for (int i = 0; i < 8; i++) {
        wpre2[i] = __builtin_amdgcn_cvt_pkrtz(Wpre[(2 * i) * 64 + lane],
                                              Wpre[(2 * i + 1) * 64 + lane]);
        wcp2[i]  = __builtin_amdgcn_cvt_pkrtz(prepP[P_WC + (2 * i) * 64 + lane],
                                              prepP[P_WC + (2 * i + 1) * 64 + lane]);
    }

    const float AP = prepP[P_A + lane], BP = prepP[P_B + lane];
    const float CPr = prepP[P_C + lane] * INV_2PI;
    const float AF = prepF[P_A + lane], BF = prepF[P_B + lane];
    const float CFr = prepF[P_C + lane] * INV_2PI;

    const int wave = __builtin_amdgcn_readfirstlane((int)((blockIdx.x * blockDim.x + threadIdx.x) >> 6));
    const int nw   = (gridDim.x * blockDim.x) >> 6;
    float s1 = 0.f, s2 = 0.f;

    auto prefetch = [&](int v, int& sb, int& m, uint2& u) {
        sb = __builtin_amdgcn_readfirstlane(start[v]);
        int se = __builtin_amdgcn_readfirstlane(start[v + 1]);
        m = se - sb;
        int ms0 = min(m, 15);
        int row = min(rq, ms0);
        int ridx = sortedIdx[sb + row];        // padded; value unused when row==ms0
        const float* bp = (row == ms0) ? (feat + (size_t)v * CIN)
                                       : (xyz  + (size_t)ridx * CIN);
        float4 q = *(const float4*)(bp + cc * 4);
        u.x = bc_u(__builtin_amdgcn_cvt_pkrtz(q.x, q.y));
        u.y = bc_u(__builtin_amdgcn_cvt_pkrtz(q.z, q.w));
    };

    auto pointmath = [&](const uint2* buf, int j, v2f& acc) {
        uint4 a = ((const uint4*)buf)[j * 2 + 0];   // uniform -> broadcast
        uint4 b = ((const uint4*)buf)[j * 2 + 1];
        v2h xs[8] = {bc_h(a.x), bc_h(a.y), bc_h(a.z), bc_h(a.w),
                     bc_h(b.x), bc_h(b.y), bc_h(b.z), bc_h(b.w)};
        float dx = 0.f, dw = 0.f;
#pragma unroll
        for (int i = 0; i < 8; i++) {
            dx = __builtin_amdgcn_fdot2(xs[i], wpre2[i], dx, false);
            dw = __builtin_amdgcn_fdot2(xs[i], wcp2[i],  dw, false);
        }
        float p  = fmaf(AP, dx, BP);
        float r  = fmaf(dw, INV_2PI, CPr);
        float sv = __builtin_amdgcn_sinf(r);
        float cv = __builtin_amdgcn_cosf(r);
        acc += p * (v2f){sv, cv};
    };

    int v = wave;
    int sb = 0, m = 0;
    uint2* cur = bufA;
    uint2* nxt = bufB;
    if (v < V) {
        uint2 u; prefetch(v, sb, m, u);
        cur[wslot] = u;                        // ds_write_b64
    }

    while (v < V) {
        const int vn = v + nw;
        int sbn = 0, mn = 0; uint2 un = {};
        if (vn < V) prefetch(vn, sbn, mn, un); // VMEM in flight during compute

        const int ms0 = min(m, 15);
        v2f acc = (v2f){0.f, 0.f};

        for (int j = 0; j < ms0; j++) pointmath(cur, j, acc);

        // remainder rows for big voxels (m > 15), rare
        for (int base = 15; base < m; base += 16) {
            const int msr  = min(16, m - base);
            const int rowc = min(rq, msr - 1);
            int ridx = sortedIdx[sb + base + rowc];
            float4 q = *(const float4*)(xyz + (size_t)ridx * CIN + cc * 4);
            uint2 u;
            u.x = bc_u(__builtin_amdgcn_cvt_pkrtz(q.x, q.y));
            u.y = bc_u(__builtin_amdgcn_cvt_pkrtz(q.z, q.w));
            remb[wslot] = u;
            for (int j = 0; j < msr; j++) pointmath(remb, j, acc);
        }

        // center row (slot ms0): dx with wpre2, dw with sWcF2 (per-lane)
        {
            uint4 a = ((const uint4*)cur)[ms0 * 2 + 0];
            uint4 b = ((const uint4*)cur)[ms0 * 2 + 1];
            v2h xs[8] = {bc_h(a.x), bc_h(a.y), bc_h(a.z), bc_h(a.w),
                         bc_h(b.x), bc_h(b.y), bc_h(b.z), bc_h(b.w)};
            float dx = 0.f, dw = 0.f;
#pragma unroll
            for (int i = 0; i < 8; i++) {
                dx = __builtin_amdgcn_fdot2(xs[i], wpre2[i], dx, false);
                dw = __builtin_amdgcn_fdot2(xs[i], bc_h(sWcF2[i * 64 + lane]), dw, false);
            }
            float f  = fmaf(AF, dx, BF);
            float r  = fmaf(dw, INV_2PI, CFr);
            float sv = __builtin_amdgcn_sinf(r);
            float cv = __builtin_amdgcn_cosf(r);
            float cs = f * sv, ccn = f * cv;
            float fin = fmaf(acc.x + cs, cs, (acc.y + ccn) * ccn);
            outFinal[(size_t)v * 64 + lane] = fin;
            s1 += fin;
            s2 = fmaf(fin, fin, s2);
        }

        if (vn < V) nxt[wslot] = un;           // stage next voxel
        uint2* tmp = cur; cur = nxt; nxt = tmp;
        v = vn; sb = sbn; m = mn;
    }

    __shared__ float sh1[4][64], sh2[4][64];
    sh1[wid][lane] = s1; sh2[wid][lane] = s2;
    __syncthreads();
    if (threadIdx.x < 64) {
        float t1 = sh1[0][lane] + sh1[1][lane] + sh1[2][lane] + sh1[3][lane];
        float t2 = sh2[0][lane] + sh2[1][lane] + sh2[2][lane] + sh2[3][lane];
        float* row = statsPart + (size_t)(blockIdx.x & 63) * 128;
        atomicAdd(row + lane, t1);
        atomicAdd(row + 64 + lane, t2);
    }
}

// ---------------- normalize + relu, stats reduced per-block ----------------
__global__ __launch_bounds__(256) void norm_kernel(float* __restrict__ out,
                                                   const float* __restrict__ sp,
                                                   const float* __restrict__ gn,
                                                   const float* __restrict__ bnb,
                                                   int V, size_t n4)
{
    __shared__ float sNs[64], sNb[64];
    const int t = threadIdx.x;
    if (t < 64) {
        double u1 = 0.0, u2 = 0.0;
#pragma unroll 4
        for (int r = 0; r < 64; r++) {
            u1 += (double)sp[(size_t)r * 128 + t];
            u2 += (double)sp[(size_t)r * 128 + 64 + t];
        }
        double mean = u1 / (double)V;
        double var  = u2 / (double)V - mean * mean;
        double ns   = (double)gn[t] / sqrt(var + BN_EPS);
        sNs[t] = (float)ns;
        sNb[t] = (float)((double)bnb[t] - ns * mean);
    }
    __syncthreads();

    const float4* ns4 = (const float4*)sNs;
    const float4* nb4 = (const float4*)sNb;
    float4* o4 = (float4*)out;
    size_t i = (size_t)blockIdx.x * blockDim.x + threadIdx.x;
    size_t stride = (size_t)gridDim.x * blockDim.x;
    for (; i < n4; i += stride) {
        int g = (int)(i & 15);
        float4 sc = ns4[g], bi = nb4[g];
        float4 w = o4[i];
        w.x = fmaxf(0.f, fmaf(sc.x, w.x, bi.x));
        w.y = fmaxf(0.f, fmaf(sc.y, w.y, bi.y));
        w.z = fmaxf(0.f, fmaf(sc.z, w.z, bi.z));
        w.w = fmaxf(0.f, fmaf(sc.w, w.w, bi.w));
        o4[i] = w;
    }
}

extern "C" void kernel_launch(void* const* d_in, const int* in_sizes, int n_in,
                              void* d_out, int out_size, void* d_ws, size_t ws_size,
                              hipStream_t stream)
{
    const float* feat  = (const float*)d_in[0];
    const float* xyz   = (const float*)d_in[1];
    const int*   unq   = (const int*)d_in[2];
    const float* Wpre  = (const float*)d_in[3];
    const float* bpre  = (const float*)d_in[4];
    const float* gpre  = (const float*)d_in[5];
    const float* bepre = (const float*)d_in[6];
    const float* Wpos  = (const float*)d_in[7];
    const float* bpos  = (const float*)d_in[8];
    const float* gn    = (const float*)d_in[9];
    const float* bnb   = (const float*)d_in[10];

    const int V = in_sizes[0] / CIN;
    const int N = in_sizes[1] / CIN;
    const int nch = (V + CHUNK - 1) / CHUNK;

    char* ws = (char*)d_ws;
    size_t off = 0;
    auto alloc = [&](size_t bytes) { void* p = ws + off; off += (bytes + 255) & ~size_t(255); return p; };

    // zeroed region first: cnt, cursor, statsPart (one memset)
    int*   cnt       = (int*)alloc((size_t)V * 4);
    int*   cursor    = (int*)alloc((size_t)V * 4);
    float* statsPart = (float*)alloc(64 * 128 * 4);
    const size_t zeroBytes = off;

    int*   start     = (int*)alloc((size_t)(V + 1) * 4);
    int*   chunkSum  = (int*)alloc(256 * 4);
    int*   chunkBase = (int*)alloc(256 * 4);
    int*   sortedIdx = (int*)alloc((size_t)(N + 64) * 4);  // +64 pad for clamped gather

    float* partP = (float*)alloc((size_t)MB * NMOM * 4);
    float* partF = (float*)alloc((size_t)MB * NMOM * 4);
    float* prepP = (float*)alloc(P_SZ * 4);
    float* prepF = (float*)alloc(P_SZ * 4);

    hipMemsetAsync(d_ws, 0, zeroBytes, stream);

    moments2_kernel<<<2 * MB, 256, 0, stream>>>(xyz, N, feat, V, unq, cnt, partP, partF);
    scan_a<<<nch, 256, 0, stream>>>(cnt, V, chunkSum);
    scan_b<<<1, 256, 0, stream>>>(chunkSum, nch, chunkBase, start, V, N);
    scan_c<<<nch, 64, 0, stream>>>(cnt, V, chunkBase, start);
    scatter_kernel<<<1024, 256, 0, stream>>>(unq, N, start, cursor, sortedIdx);
    prep_kernel<<<2, 256, 0, stream>>>(Wpre, bpre, gpre, bepre, Wpos, bpos,
                                       partP, partF, MB, N, V, prepP, prepF);
    fused_pass<<<2048, 256, 0, stream>>>(xyz, feat, sortedIdx, start, Wpre,
                                         prepP, prepF, (float*)d_out, statsPart, V);
    norm_kernel<<<512, 256, 0, stream>>>((float*)d_out, statsPart, gn, bnb, V,
                                         (size_t)out_size / 4);
}

// Round 16
// 225.265 us; speedup vs baseline: 1.1564x; 1.0792x over previous
//
#include <hip/hip_runtime.h>
#include <cstdint>
#include <cstddef>

constexpr int CIN  = 16;
constexpr int COUT = 64;
constexpr int NMOM = 16 + 136;          // 16 sums + 136 upper-tri products
constexpr double BN_EPS = 1e-3;

typedef float v2f __attribute__((ext_vector_type(2)));
typedef __fp16 v2h __attribute__((ext_vector_type(2)));   // matches cvt_pkrtz/fdot2 builtin type
constexpr float INV_2PI = 0.15915494309189535f;

// prep layout (floats): A[64], B[64], c[64], Wc[16*64]
constexpr int P_A = 0, P_B = 64, P_C = 128, P_WC = 192, P_SZ = 192 + CIN * COUT;

constexpr int CHUNK = 512;              // scan chunk
constexpr int MB = 256;                 // moments blocks per input; 1 partial row/block

__device__ __forceinline__ unsigned bc_u(v2h h) { return __builtin_bit_cast(unsigned, h); }
__device__ __forceinline__ v2h bc_h(unsigned u) { return __builtin_bit_cast(v2h, u); }

// ---------------- moments + histogram (one launch) -------------------------
// __launch_bounds__(256, 2): acc[152]+staging ~185 VGPR fits under the
// 256-VGPR/2-waves-per-SIMD cap -> no spill (R14: 96 VGPR + 31.8 MB spill
// writes) AND keeps 2 waves/SIMD TLP (R15's (256,1) allowed a 1-wave alloc).
__global__ __launch_bounds__(256, 2) void moments2_kernel(const float* __restrict__ xyz, int n1,
                                                       const float* __restrict__ feat, int n2,
                                                       const int* __restrict__ unq,
                                                       int* __restrict__ cnt,
                                                       float* __restrict__ partP,
                                                       float* __restrict__ partF)
{
    const int bb  = blockIdx.x;
    const bool second = (bb >= MB);
    const float* x = second ? feat : xyz;
    const int    n = second ? n2 : n1;
    float* part    = second ? partF : partP;
    const int blk  = second ? bb - MB : bb;

    float acc[NMOM];
#pragma unroll
    for (int i = 0; i < NMOM; i++) acc[i] = 0.f;

    int tid = blk * 256 + threadIdx.x;
    int stride = MB * 256;
    for (int r = tid; r < n; r += stride) {
        const float4* xp = (const float4*)(x + (size_t)r * CIN);
        float4 a0 = xp[0], a1 = xp[1], a2 = xp[2], a3 = xp[3];
        if (!second) atomicAdd(cnt + unq[r], 1);     // fused histogram
        float v[16] = {a0.x,a0.y,a0.z,a0.w, a1.x,a1.y,a1.z,a1.w,
                       a2.x,a2.y,a2.z,a2.w, a3.x,a3.y,a3.z,a3.w};
#pragma unroll
        for (int i = 0; i < 16; i++) acc[i] += v[i];
        int c = 16;
#pragma unroll
        for (int k = 0; k < 16; k++)
#pragma unroll
            for (int l = k; l < 16; l++) { acc[c] = fmaf(v[k], v[l], acc[c]); c++; }
    }

    const int lane = threadIdx.x & 63;
    const int wid  = threadIdx.x >> 6;
    float r0 = 0.f, r1 = 0.f, r2 = 0.f;
#pragma unroll
    for (int i = 0; i < NMOM; i++) {
        float s = acc[i];
#pragma unroll
        for (int off = 1; off < 64; off <<= 1) s += __shfl_xor(s, off, 64);
        if (i < 64)       { if (lane == i)       r0 = s; }
        else if (i < 128) { if (lane == i - 64)  r1 = s; }
        else              { if (lane == i - 128) r2 = s; }
    }

    __shared__ float red[4][NMOM];
    red[wid][lane] = r0;
    red[wid][64 + lane] = r1;
    if (lane < NMOM - 128) red[wid][128 + lane] = r2;
    __syncthreads();
    int t = threadIdx.x;
    if (t < NMOM) {
        float s = red[0][t] + red[1][t] + red[2][t] + red[3][t];
        part[(size_t)blk * NMOM + t] = s;
    }
}

// ---------------- prep: fold BN analytically into the linears --------------
__global__ __launch_bounds__(256) void prep_kernel(const float* __restrict__ Wpre, const float* __restrict__ bpre,
                            const float* __restrict__ gpre, const float* __restrict__ bepre,
                            const float* __restrict__ Wpos, const float* __restrict__ bpos,
                            const float* __restrict__ partP, const float* __restrict__ partF,
                            int nrows, int Np, int Vv,
                            float* __restrict__ prepP, float* __restrict__ prepF)
{
    const int t  = threadIdx.x;   // 0..255
    const int br = blockIdx.x;    // 0 or 1
    const float* part = br ? partF : partP;
    const double n    = br ? (double)Vv : (double)Np;
    const double inv_n = 1.0 / n;
    float* prep       = br ? prepF : prepP;

    __shared__ float sWpre[CIN * 64];    // 16x64
    __shared__ float sWpos[64 * 64];     // 64x64
    __shared__ double mom[NMOM];
    __shared__ double sS[64], sB[64];

    for (int i = t; i < CIN * 64; i += 256) sWpre[i] = Wpre[i];
    for (int i = t; i < 64 * 64; i += 256)  sWpos[i] = Wpos[i];

    if (t < NMOM) {
        double s0 = 0, s1 = 0, s2 = 0, s3 = 0, s4 = 0, s5 = 0, s6 = 0, s7 = 0;
        int r = 0;
        for (; r + 8 <= nrows; r += 8) {
            s0 += (double)part[(size_t)(r + 0) * NMOM + t];
            s1 += (double)part[(size_t)(r + 1) * NMOM + t];
            s2 += (double)part[(size_t)(r + 2) * NMOM + t];
            s3 += (double)part[(size_t)(r + 3) * NMOM + t];
            s4 += (double)part[(size_t)(r + 4) * NMOM + t];
            s5 += (double)part[(size_t)(r + 5) * NMOM + t];
            s6 += (double)part[(size_t)(r + 6) * NMOM + t];
            s7 += (double)part[(size_t)(r + 7) * NMOM + t];
        }
        for (; r < nrows; r++) s0 += (double)part[(size_t)r * NMOM + t];
        mom[t] = ((s0 + s1) + (s2 + s3)) + ((s4 + s5) + (s6 + s7));
    }
    __syncthreads();

    if (t < 64) {
        const int k = t;
        double mu[16];
#pragma unroll
        for (int i = 0; i < 16; i++) mu[i] = mom[i] * inv_n;
        double w[16];
#pragma unroll
        for (int i = 0; i < 16; i++) w[i] = (double)sWpre[i * 64 + k];

        double mk = (double)bpre[k];
#pragma unroll
        for (int i = 0; i < 16; i++) mk += mu[i] * w[i];

        double var = 0.0;
        int c = 16;
#pragma unroll
        for (int a = 0; a < 16; a++)
#pragma unroll
            for (int l = a; l < 16; l++) {
                double cov = mom[c] * inv_n - mu[a] * mu[l]; c++;
                var += (a == l ? 1.0 : 2.0) * w[a] * w[l] * cov;
            }

        double s_k = (double)gpre[k] / sqrt(var + BN_EPS);
        double B_k = (double)bepre[k] + s_k * ((double)bpre[k] - mk);
        sS[k] = s_k; sB[k] = B_k;
    }
    __syncthreads();

    if (t < 64) {
        const int k = t;
        double c0 = (double)bpos[k], c1 = 0.0;
        for (int j = 0; j < 64; j += 2) {
            c0 += sB[j]     * (double)sWpos[j * 64 + k];
            c1 += sB[j + 1] * (double)sWpos[(j + 1) * 64 + k];
        }
        prep[P_A + k] = (float)sS[k];
        prep[P_B + k] = (float)sB[k];
        prep[P_C + k] = (float)(c0 + c1);
    }

    {
        const int k  = t & 63;
        const int i0 = t >> 6;
        for (int i = i0; i < 16; i += 4) {
            double w0 = 0.0, w1 = 0.0;
            for (int j = 0; j < 64; j += 2) {
                w0 += (double)sWpre[i * 64 + j]     * sS[j]     * (double)sWpos[j * 64 + k];
                w1 += (double)sWpre[i * 64 + j + 1] * sS[j + 1] * (double)sWpos[(j + 1) * 64 + k];
            }
            prep[P_WC + i * 64 + k] = (float)(w0 + w1);
        }
    }
}

// ---------------- scan stage a: per-chunk sums ------------------------------
__global__ __launch_bounds__(256) void scan_a(const int* __restrict__ cnt, int V,
                                              int* __restrict__ chunkSum)
{
    const int b = blockIdx.x, t = threadIdx.x;
    int base = b * CHUNK;
    int i0 = base + t * 2, i1 = i0 + 1;
    int s = ((i0 < V) ? cnt[i0] : 0) + ((i1 < V) ? cnt[i1] : 0);
    __shared__ int red[4];
    const int lane = t & 63, wid = t >> 6;
#pragma unroll
    for (int off = 1; off < 64; off <<= 1) s += __shfl_xor(s, off, 64);
    if (lane == 0) red[wid] = s;
    __syncthreads();
    if (t == 0) chunkSum[b] = red[0] + red[1] + red[2] + red[3];
}

// ---------------- scan stage b: exclusive scan of chunk sums (<=256) --------
__global__ __launch_bounds__(256) void scan_b(const int* __restrict__ chunkSum, int nch,
                                              int* __restrict__ chunkBase,
                                              int* __restrict__ start, int V, int N)
{
    const int t = threadIdx.x;
    __shared__ int a[256];
    int v = (t < nch) ? chunkSum[t] : 0;
    a[t] = v;
    __syncthreads();
    for (int off = 1; off < 256; off <<= 1) {
        int add = (t >= off) ? a[t - off] : 0;
        __syncthreads();
        a[t] += add;
        __syncthreads();
    }
    chunkBase[t] = a[t] - v;   // exclusive
    if (t == 0) start[V] = N;
}

// ---------------- scan stage c: per-chunk exclusive scan -> start ----------
__global__ __launch_bounds__(64) void scan_c(const int* __restrict__ cnt, int V,
                                             const int* __restrict__ chunkBase,
                                             int* __restrict__ start)
{
    const int b = blockIdx.x;
    const int lane = threadIdx.x;
    const int base = b * CHUNK + lane * 8;
    int e[8];
    int run = 0;
#pragma unroll
    for (int j = 0; j < 8; j++) {
        int idx = base + j;
        int c = (idx < V) ? cnt[idx] : 0;
        e[j] = run;
        run += c;
    }
    int incl = run;
#pragma unroll
    for (int off = 1; off < 64; off <<= 1) {
        int vv = __shfl_up(incl, off, 64);
        if (lane >= off) incl += vv;
    }
    int excl = incl - run;
    int myBase = chunkBase[b] + excl;
#pragma unroll
    for (int j = 0; j < 8; j++) {
        int idx = base + j;
        if (idx < V) start[idx] = myBase + e[j];
    }
}

// ---------------- scatter: point indices into voxel-sorted order -----------
__global__ __launch_bounds__(256) void scatter_kernel(const int* __restrict__ unq, int N,
                                                      const int* __restrict__ start,
                                                      int* __restrict__ cursor,
                                                      int* __restrict__ sortedIdx)
{
    int t = blockIdx.x * blockDim.x + threadIdx.x;
    int stride = gridDim.x * blockDim.x;
    for (; t < N; t += stride) {
        int v = unq[t];
        int pos = start[v] + atomicAdd(cursor + v, 1);
        sortedIdx[pos] = t;
    }
}

// ---------------- fused voxel pass: f16 LDS rows + v_dot2_f32_f16 ----------
__global__ __launch_bounds__(256) void fused_pass(const float* __restrict__ xyz,
                                                  const float* __restrict__ feat,
                                                  const int* __restrict__ sortedIdx,
                                                  const int* __restrict__ start,
                                                  const float* __restrict__ Wpre,
                                                  const float* __restrict__ prepP,
                                                  const float* __restrict__ prepF,
                                                  float* __restrict__ outFinal,
                                                  float* __restrict__ statsPart, int V)
{
    const int lane = threadIdx.x & 63;
    const int wid  = threadIdx.x >> 6;
    const int rq   = lane >> 2;      // row slot 0..15
    const int cc   = lane & 3;       // quarter within row

    // per-wave LDS: 3 buffers x 16 rows x 16 halfs (512 B each)
    __shared__ uint2 ldsq[4][3][64];
    __shared__ unsigned sWcF2[8 * 64];      // center dw weights, half2-packed
    uint2* bufA = ldsq[wid][0];
    uint2* bufB = ldsq[wid][1];
    uint2* remb = ldsq[wid][2];
    const int wslot = rq * 4 + cc;

    for (int i = threadIdx.x; i < 8 * 64; i += 256) {
        int fi = i >> 6, ch = i & 63;
        sWcF2[i] = bc_u(__builtin_amdgcn_cvt_pkrtz(prepF[P_WC + (2 * fi) * 64 + ch],
                                                   prepF[P_WC + (2 * fi + 1) * 64 + ch]));
    }
    __syncthreads();

    v2h wpre2[8], wcp2[8];
#pragma unroll
    for (int i = 0; i < 8; i++) {
        wpre2[i] = __builtin_amdgcn_cvt_pkrtz(Wpre[(2 * i) * 64 + lane],
                                              Wpre[(2 * i + 1) * 64 + lane]);
        wcp2[i]  = __builtin_amdgcn_cvt_pkrtz(prepP[P_WC + (2 * i) * 64 + lane],
                                              prepP[P_WC + (2 * i + 1) * 64 + lane]);
    }

    const float AP = prepP[P_A + lane], BP = prepP[P_B + lane];
    const float CPr = prepP[P_C + lane] * INV_2PI;
    const float AF = prepF[P_A + lane], BF = prepF[P_B + lane];
    const float CFr = prepF[P_C + lane] * INV_2PI;

    const int wave = __builtin_amdgcn_readfirstlane((int)((blockIdx.x * blockDim.x + threadIdx.x) >> 6));
    const int nw   = (gridDim.x * blockDim.x) >> 6;
    float s1 = 0.f, s2 = 0.f;

    auto prefetch = [&](int v, int& sb, int& m, uint2& u) {
        sb = __builtin_amdgcn_readfirstlane(start[v]);
        int se = __builtin_amdgcn_readfirstlane(start[v + 1]);
        m = se - sb;
        int ms0 = min(m, 15);
        int row = min(rq, ms0);
        int ridx = sortedIdx[sb + row];        // padded; value unused when row==ms0
        const float* bp = (row == ms0) ? (feat + (size_t)v * CIN)
                                       : (xyz  + (size_t)ridx * CIN);
        float4 q = *(const float4*)(bp + cc * 4);
        u.x = bc_u(__builtin_amdgcn_cvt_pkrtz(q.x, q.y));
        u.y = bc_u(__builtin_amdgcn_cvt_pkrtz(q.z, q.w));
    };

    auto pointmath = [&](const uint2* buf, int j, v2f& acc) {
        uint4 a = ((const uint4*)buf)[j * 2 + 0];   // uniform -> broadcast
        uint4 b = ((const uint4*)buf)[j * 2 + 1];
        v2h xs[8] = {bc_h(a.x), bc_h(a.y), bc_h(a.z), bc_h(a.w),
                     bc_h(b.x), bc_h(b.y), bc_h(b.z), bc_h(b.w)};
        float dx = 0.f, dw = 0.f;
#pragma unroll
        for (int i = 0; i < 8; i++) {
            dx = __builtin_amdgcn_fdot2(xs[i], wpre2[i], dx, false);
            dw = __builtin_amdgcn_fdot2(xs[i], wcp2[i],  dw, false);
        }
        float p  = fmaf(AP, dx, BP);
        float r  = fmaf(dw, INV_2PI, CPr);
        float sv = __builtin_amdgcn_sinf(r);
        float cv = __builtin_amdgcn_cosf(r);
        acc += p * (v2f){sv, cv};
    };

    int v = wave;
    int sb = 0, m = 0;
    uint2* cur = bufA;
    uint2* nxt = bufB;
    if (v < V) {
        uint2 u; prefetch(v, sb, m, u);
        cur[wslot] = u;                        // ds_write_b64
    }

    while (v < V) {
        const int vn = v + nw;
        int sbn = 0, mn = 0; uint2 un = {};
        if (vn < V) prefetch(vn, sbn, mn, un); // VMEM in flight during compute

        const int ms0 = min(m, 15);
        v2f acc = (v2f){0.f, 0.f};

        for (int j = 0; j < ms0; j++) pointmath(cur, j, acc);

        // remainder rows for big voxels (m > 15), rare
        for (int base = 15; base < m; base += 16) {
            const int msr  = min(16, m - base);
            const int rowc = min(rq, msr - 1);
            int ridx = sortedIdx[sb + base + rowc];
            float4 q = *(const float4*)(xyz + (size_t)ridx * CIN + cc * 4);
            uint2 u;
            u.x = bc_u(__builtin_amdgcn_cvt_pkrtz(q.x, q.y));
            u.y = bc_u(__builtin_amdgcn_cvt_pkrtz(q.z, q.w));
            remb[wslot] = u;
            for (int j = 0; j < msr; j++) pointmath(remb, j, acc);
        }

        // center row (slot ms0): dx with wpre2, dw with sWcF2 (per-lane)
        {
            uint4 a = ((const uint4*)cur)[ms0 * 2 + 0];
            uint4 b = ((const uint4*)cur)[ms0 * 2 + 1];
            v2h xs[8] = {bc_h(a.x), bc_h(a.y), bc_h(a.z), bc_h(a.w),
                         bc_h(b.x), bc_h(b.y), bc_h(b.z), bc_h(b.w)};
            float dx = 0.f, dw = 0.f;
#pragma unroll
            for (int i = 0; i < 8; i++) {
                dx = __builtin_amdgcn_fdot2(xs[i], wpre2[i], dx, false);
                dw = __builtin_amdgcn_fdot2(xs[i], bc_h(sWcF2[i * 64 + lane]), dw, false);
            }
            float f  = fmaf(AF, dx, BF);
            float r  = fmaf(dw, INV_2PI, CFr);
            float sv = __builtin_amdgcn_sinf(r);
            float cv = __builtin_amdgcn_cosf(r);
            float cs = f * sv, ccn = f * cv;
            float fin = fmaf(acc.x + cs, cs, (acc.y + ccn) * ccn);
            outFinal[(size_t)v * 64 + lane] = fin;
            s1 += fin;
            s2 = fmaf(fin, fin, s2);
        }

        if (vn < V) nxt[wslot] = un;           // stage next voxel
        uint2* tmp = cur; cur = nxt; nxt = tmp;
        v = vn; sb = sbn; m = mn;
    }

    __shared__ float sh1[4][64], sh2[4][64];
    sh1[wid][lane] = s1; sh2[wid][lane] = s2;
    __syncthreads();
    if (threadIdx.x < 64) {
        float t1 = sh1[0][lane] + sh1[1][lane] + sh1[2][lane] + sh1[3][lane];
        float t2 = sh2[0][lane] + sh2[1][lane] + sh2[2][lane] + sh2[3][lane];
        float* row = statsPart + (size_t)(blockIdx.x & 63) * 128;
        atomicAdd(row + lane, t1);
        atomicAdd(row + 64 + lane, t2);
    }
}

// ---------------- normalize + relu, stats reduced per-block ----------------
__global__ __launch_bounds__(256) void norm_kernel(float* __restrict__ out,
                                                   const float* __restrict__ sp,
                                                   const float* __restrict__ gn,
                                                   const float* __restrict__ bnb,
                                                   int V, size_t n4)
{
    __shared__ float sNs[64], sNb[64];
    const int t = threadIdx.x;
    if (t < 64) {
        double u1 = 0.0, u2 = 0.0;
#pragma unroll 4
        for (int r = 0; r < 64; r++) {
            u1 += (double)sp[(size_t)r * 128 + t];
            u2 += (double)sp[(size_t)r * 128 + 64 + t];
        }
        double mean = u1 / (double)V;
        double var  = u2 / (double)V - mean * mean;
        double ns   = (double)gn[t] / sqrt(var + BN_EPS);
        sNs[t] = (float)ns;
        sNb[t] = (float)((double)bnb[t] - ns * mean);
    }
    __syncthreads();

    const float4* ns4 = (const float4*)sNs;
    const float4* nb4 = (const float4*)sNb;
    float4* o4 = (float4*)out;
    size_t i = (size_t)blockIdx.x * blockDim.x + threadIdx.x;
    size_t stride = (size_t)gridDim.x * blockDim.x;
    for (; i < n4; i += stride) {
        int g = (int)(i & 15);
        float4 sc = ns4[g], bi = nb4[g];
        float4 w = o4[i];
        w.x = fmaxf(0.f, fmaf(sc.x, w.x, bi.x));
        w.y = fmaxf(0.f, fmaf(sc.y, w.y, bi.y));
        w.z = fmaxf(0.f, fmaf(sc.z, w.z, bi.z));
        w.w = fmaxf(0.f, fmaf(sc.w, w.w, bi.w));
        o4[i] = w;
    }
}

extern "C" void kernel_launch(void* const* d_in, const int* in_sizes, int n_in,
                              void* d_out, int out_size, void* d_ws, size_t ws_size,
                              hipStream_t stream)
{
    const float* feat  = (const float*)d_in[0];
    const float* xyz   = (const float*)d_in[1];
    const int*   unq   = (const int*)d_in[2];
    const float* Wpre  = (const float*)d_in[3];
    const float* bpre  = (const float*)d_in[4];
    const float* gpre  = (const float*)d_in[5];
    const float* bepre = (const float*)d_in[6];
    const float* Wpos  = (const float*)d_in[7];
    const float* bpos  = (const float*)d_in[8];
    const float* gn    = (const float*)d_in[9];
    const float* bnb   = (const float*)d_in[10];

    const int V = in_sizes[0] / CIN;
    const int N = in_sizes[1] / CIN;
    const int nch = (V + CHUNK - 1) / CHUNK;

    char* ws = (char*)d_ws;
    size_t off = 0;
    auto alloc = [&](size_t bytes) { void* p = ws + off; off += (bytes + 255) & ~size_t(255); return p; };

    // zeroed region first: cnt, cursor, statsPart (one memset)
    int*   cnt       = (int*)alloc((size_t)V * 4);
    int*   cursor    = (int*)alloc((size_t)V * 4);
    float* statsPart = (float*)alloc(64 * 128 * 4);
    const size_t zeroBytes = off;

    int*   start     = (int*)alloc((size_t)(V + 1) * 4);
    int*   chunkSum  = (int*)alloc(256 * 4);
    int*   chunkBase = (int*)alloc(256 * 4);
    int*   sortedIdx = (int*)alloc((size_t)(N + 64) * 4);  // +64 pad for clamped gather

    float* partP = (float*)alloc((size_t)MB * NMOM * 4);
    float* partF = (float*)alloc((size_t)MB * NMOM * 4);
    float* prepP = (float*)alloc(P_SZ * 4);
    float* prepF = (float*)alloc(P_SZ * 4);

    hipMemsetAsync(d_ws, 0, zeroBytes, stream);

    moments2_kernel<<<2 * MB, 256, 0, stream>>>(xyz, N, feat, V, unq, cnt, partP, partF);
    scan_a<<<nch, 256, 0, stream>>>(cnt, V, chunkSum);
    scan_b<<<1, 256, 0, stream>>>(chunkSum, nch, chunkBase, start, V, N);
    scan_c<<<nch, 64, 0, stream>>>(cnt, V, chunkBase, start);
    scatter_kernel<<<1024, 256, 0, stream>>>(unq, N, start, cursor, sortedIdx);
    prep_kernel<<<2, 256, 0, stream>>>(Wpre, bpre, gpre, bepre, Wpos, bpos,
                                       partP, partF, MB, N, V, prepP, prepF);
    fused_pass<<<2048, 256, 0, stream>>>(xyz, feat, sortedIdx, start, Wpre,
                                         prepP, prepF, (float*)d_out, statsPart, V);
    norm_kernel<<<512, 256, 0, stream>>>((float*)d_out, statsPart, gn, bnb, V,
                                         (size_t)out_size / 4);
}

// Round 17
// 222.335 us; speedup vs baseline: 1.1716x; 1.0132x over previous
//
#include <hip/hip_runtime.h>
#include <cstdint>
#include <cstddef>

constexpr int CIN  = 16;
constexpr int COUT = 64;
constexpr int NMOM = 16 + 136;          // 16 sums + 136 upper-tri products
constexpr double BN_EPS = 1e-3;

typedef float v2f __attribute__((ext_vector_type(2)));
typedef __fp16 v2h __attribute__((ext_vector_type(2)));   // matches cvt_pkrtz/fdot2 builtin type
constexpr float INV_2PI = 0.15915494309189535f;

// prep layout (floats): A[64], B[64], c[64], Wc[16*64]
constexpr int P_A = 0, P_B = 64, P_C = 128, P_WC = 192, P_SZ = 192 + CIN * COUT;

constexpr int CHUNK = 512;              // scan chunk
constexpr int MB = 256;                 // moments blocks per input; 1 partial row/block

__device__ __forceinline__ unsigned bc_u(v2h h) { return __builtin_bit_cast(unsigned, h); }
__device__ __forceinline__ v2h bc_h(unsigned u) { return __builtin_bit_cast(v2h, u); }

// ---------------- moments + histogram (one launch) -------------------------
// (256,2): acc[152]+staging ~185 VGPR fits under the 256-VGPR cap -> no
// spill, 2 waves/SIMD TLP. (R14: default heuristic gave 96 VGPR + 31.8 MB
// of scratch-spill writes, 88 us.)
__global__ __launch_bounds__(256, 2) void moments2_kernel(const float* __restrict__ xyz, int n1,
                                                       const float* __restrict__ feat, int n2,
                                                       const int* __restrict__ unq,
                                                       int* __restrict__ cnt,
                                                       float* __restrict__ partP,
                                                       float* __restrict__ partF)
{
    const int bb  = blockIdx.x;
    const bool second = (bb >= MB);
    const float* x = second ? feat : xyz;
    const int    n = second ? n2 : n1;
    float* part    = second ? partF : partP;
    const int blk  = second ? bb - MB : bb;

    float acc[NMOM];
#pragma unroll
    for (int i = 0; i < NMOM; i++) acc[i] = 0.f;

    int tid = blk * 256 + threadIdx.x;
    int stride = MB * 256;
    for (int r = tid; r < n; r += stride) {
        const float4* xp = (const float4*)(x + (size_t)r * CIN);
        float4 a0 = xp[0], a1 = xp[1], a2 = xp[2], a3 = xp[3];
        if (!second) atomicAdd(cnt + unq[r], 1);     // fused histogram
        float v[16] = {a0.x,a0.y,a0.z,a0.w, a1.x,a1.y,a1.z,a1.w,
                       a2.x,a2.y,a2.z,a2.w, a3.x,a3.y,a3.z,a3.w};
#pragma unroll
        for (int i = 0; i < 16; i++) acc[i] += v[i];
        int c = 16;
#pragma unroll
        for (int k = 0; k < 16; k++)
#pragma unroll
            for (int l = k; l < 16; l++) { acc[c] = fmaf(v[k], v[l], acc[c]); c++; }
    }

    const int lane = threadIdx.x & 63;
    const int wid  = threadIdx.x >> 6;
    float r0 = 0.f, r1 = 0.f, r2 = 0.f;
#pragma unroll
    for (int i = 0; i < NMOM; i++) {
        float s = acc[i];
#pragma unroll
        for (int off = 1; off < 64; off <<= 1) s += __shfl_xor(s, off, 64);
        if (i < 64)       { if (lane == i)       r0 = s; }
        else if (i < 128) { if (lane == i - 64)  r1 = s; }
        else              { if (lane == i - 128) r2 = s; }
    }

    __shared__ float red[4][NMOM];
    red[wid][lane] = r0;
    red[wid][64 + lane] = r1;
    if (lane < NMOM - 128) red[wid][128 + lane] = r2;
    __syncthreads();
    int t = threadIdx.x;
    if (t < NMOM) {
        float s = red[0][t] + red[1][t] + red[2][t] + red[3][t];
        part[(size_t)blk * NMOM + t] = s;
    }
}

// ---------------- prep (blocks 0,1) + scan_a (blocks 2..nch+1) -------------
__global__ __launch_bounds__(256) void prep_scanA(const float* __restrict__ Wpre, const float* __restrict__ bpre,
                            const float* __restrict__ gpre, const float* __restrict__ bepre,
                            const float* __restrict__ Wpos, const float* __restrict__ bpos,
                            const float* __restrict__ partP, const float* __restrict__ partF,
                            int nrows, int Np, int Vv,
                            float* __restrict__ prepP, float* __restrict__ prepF,
                            const int* __restrict__ cnt, int V,
                            int* __restrict__ chunkSum)
{
    const int t = threadIdx.x;   // 0..255
    const int lane = t & 63, wid = t >> 6;

    if (blockIdx.x >= 2) {
        // ---- scan_a: per-chunk sum of cnt ----
        const int b = blockIdx.x - 2;
        int base = b * CHUNK;
        int i0 = base + t * 2, i1 = i0 + 1;
        int s = ((i0 < V) ? cnt[i0] : 0) + ((i1 < V) ? cnt[i1] : 0);
        __shared__ int redc[4];
#pragma unroll
        for (int off = 1; off < 64; off <<= 1) s += __shfl_xor(s, off, 64);
        if (lane == 0) redc[wid] = s;
        __syncthreads();
        if (t == 0) chunkSum[b] = redc[0] + redc[1] + redc[2] + redc[3];
        return;
    }

    // ---- prep branch ----
    const int br = blockIdx.x;    // 0 or 1
    const float* part = br ? partF : partP;
    const double n    = br ? (double)Vv : (double)Np;
    const double inv_n = 1.0 / n;
    float* prep       = br ? prepF : prepP;

    __shared__ float sWpre[CIN * 64];    // 16x64
    __shared__ float sWpos[64 * 64];     // 64x64
    __shared__ double mom[NMOM];
    __shared__ double sS[64], sB[64];

    for (int i = t; i < CIN * 64; i += 256) sWpre[i] = Wpre[i];
    for (int i = t; i < 64 * 64; i += 256)  sWpos[i] = Wpos[i];

    if (t < NMOM) {
        double s0 = 0, s1 = 0, s2 = 0, s3 = 0, s4 = 0, s5 = 0, s6 = 0, s7 = 0;
        int r = 0;
        for (; r + 8 <= nrows; r += 8) {
            s0 += (double)part[(size_t)(r + 0) * NMOM + t];
            s1 += (double)part[(size_t)(r + 1) * NMOM + t];
            s2 += (double)part[(size_t)(r + 2) * NMOM + t];
            s3 += (double)part[(size_t)(r + 3) * NMOM + t];
            s4 += (double)part[(size_t)(r + 4) * NMOM + t];
            s5 += (double)part[(size_t)(r + 5) * NMOM + t];
            s6 += (double)part[(size_t)(r + 6) * NMOM + t];
            s7 += (double)part[(size_t)(r + 7) * NMOM + t];
        }
        for (; r < nrows; r++) s0 += (double)part[(size_t)r * NMOM + t];
        mom[t] = ((s0 + s1) + (s2 + s3)) + ((s4 + s5) + (s6 + s7));
    }
    __syncthreads();

    if (t < 64) {
        const int k = t;
        double mu[16];
#pragma unroll
        for (int i = 0; i < 16; i++) mu[i] = mom[i] * inv_n;
        double w[16];
#pragma unroll
        for (int i = 0; i < 16; i++) w[i] = (double)sWpre[i * 64 + k];

        double mk = (double)bpre[k];
#pragma unroll
        for (int i = 0; i < 16; i++) mk += mu[i] * w[i];

        double var = 0.0;
        int c = 16;
#pragma unroll
        for (int a = 0; a < 16; a++)
#pragma unroll
            for (int l = a; l < 16; l++) {
                double cov = mom[c] * inv_n - mu[a] * mu[l]; c++;
                var += (a == l ? 1.0 : 2.0) * w[a] * w[l] * cov;
            }

        double s_k = (double)gpre[k] / sqrt(var + BN_EPS);
        double B_k = (double)bepre[k] + s_k * ((double)bpre[k] - mk);
        sS[k] = s_k; sB[k] = B_k;
    }
    __syncthreads();

    if (t < 64) {
        const int k = t;
        double c0 = (double)bpos[k], c1 = 0.0;
        for (int j = 0; j < 64; j += 2) {
            c0 += sB[j]     * (double)sWpos[j * 64 + k];
            c1 += sB[j + 1] * (double)sWpos[(j + 1) * 64 + k];
        }
        prep[P_A + k] = (float)sS[k];
        prep[P_B + k] = (float)sB[k];
        prep[P_C + k] = (float)(c0 + c1);
    }

    {
        const int k  = t & 63;
        const int i0 = t >> 6;
        for (int i = i0; i < 16; i += 4) {
            double w0 = 0.0, w1 = 0.0;
            for (int j = 0; j < 64; j += 2) {
                w0 += (double)sWpre[i * 64 + j]     * sS[j]     * (double)sWpos[j * 64 + k];
                w1 += (double)sWpre[i * 64 + j + 1] * sS[j + 1] * (double)sWpos[(j + 1) * 64 + k];
            }
            prep[P_WC + i * 64 + k] = (float)(w0 + w1);
        }
    }
}

// ---------------- scanC: per-chunk scan + inline base + cursor zero --------
__global__ __launch_bounds__(64) void scanC(const int* __restrict__ cnt, int V, int N,
                                            const int* __restrict__ chunkSum,
                                            int* __restrict__ start,
                                            int* __restrict__ cursor)
{
    const int b = blockIdx.x;
    const int lane = threadIdx.x;

    // chunk base = sum of chunkSum[0..b-1] (redundant per block; b <= ~200)
    int pv = 0;
    for (int i = lane; i < b; i += 64) pv += chunkSum[i];
#pragma unroll
    for (int off = 1; off < 64; off <<= 1) pv += __shfl_xor(pv, off, 64);
    const int chunkBase = pv;

    const int base = b * CHUNK + lane * 8;
    int e[8];
    int run = 0;
#pragma unroll
    for (int j = 0; j < 8; j++) {
        int idx = base + j;
        int c = (idx < V) ? cnt[idx] : 0;
        e[j] = run;
        run += c;
    }
    int incl = run;
#pragma unroll
    for (int off = 1; off < 64; off <<= 1) {
        int vv = __shfl_up(incl, off, 64);
        if (lane >= off) incl += vv;
    }
    int excl = incl - run;
    int myBase = chunkBase + excl;
#pragma unroll
    for (int j = 0; j < 8; j++) {
        int idx = base + j;
        if (idx < V) { start[idx] = myBase + e[j]; cursor[idx] = 0; }
    }
    if (b == 0 && lane == 0) start[V] = N;
}

// ---------------- scatter: point indices into voxel-sorted order -----------
__global__ __launch_bounds__(256) void scatter_kernel(const int* __restrict__ unq, int N,
                                                      const int* __restrict__ start,
                                                      int* __restrict__ cursor,
                                                      int* __restrict__ sortedIdx)
{
    int t = blockIdx.x * blockDim.x + threadIdx.x;
    int stride = gridDim.x * blockDim.x;
    for (; t < N; t += stride) {
        int v = unq[t];
        int pos = start[v] + atomicAdd(cursor + v, 1);
        sortedIdx[pos] = t;
    }
}

// ---------------- fused voxel pass: f16 LDS rows + v_dot2_f32_f16 ----------
__global__ __launch_bounds__(256) void fused_pass(const float* __restrict__ xyz,
                                                  const float* __restrict__ feat,
                                                  const int* __restrict__ sortedIdx,
                                                  const int* __restrict__ start,
                                                  const float* __restrict__ Wpre,
                                                  const float* __restrict__ prepP,
                                                  const float* __restrict__ prepF,
                                                  float* __restrict__ outFinal,
                                                  float* __restrict__ statsPart, int V)
{
    const int lane = threadIdx.x & 63;
    const int wid  = threadIdx.x >> 6;
    const int rq   = lane >> 2;      // row slot 0..15
    const int cc   = lane & 3;       // quarter within row

    // per-wave LDS: 3 buffers x 16 rows x 16 halfs (512 B each)
    __shared__ uint2 ldsq[4][3][64];
    __shared__ unsigned sWcF2[8 * 64];      // center dw weights, half2-packed
    uint2* bufA = ldsq[wid][0];
    uint2* bufB = ldsq[wid][1];
    uint2* remb = ldsq[wid][2];
    const int wslot = rq * 4 + cc;

    for (int i = threadIdx.x; i < 8 * 64; i += 256) {
        int fi = i >> 6, ch = i & 63;
        sWcF2[i] = bc_u(__builtin_amdgcn_cvt_pkrtz(prepF[P_WC + (2 * fi) * 64 + ch],
                                                   prepF[P_WC + (2 * fi + 1) * 64 + ch]));
    }
    __syncthreads();

    v2h wpre2[8], wcp2[8];
#pragma unroll
    for (int i = 0; i < 8; i++) {
        wpre2[i] = __builtin_amdgcn_cvt_pkrtz(Wpre[(2 * i) * 64 + lane],
                                              Wpre[(2 * i + 1) * 64 + lane]);
        wcp2[i]  = __builtin_amdgcn_cvt_pkrtz(prepP[P_WC + (2 * i) * 64 + lane],
                                              prepP[P_WC + (2 * i + 1) * 64 + lane]);
    }

    const float AP = prepP[P_A + lane], BP = prepP[P_B + lane];
    const float CPr = prepP[P_C + lane] * INV_2PI;
    const float AF = prepF[P_A + lane], BF = prepF[P_B + lane];
    const float CFr = prepF[P_C + lane] * INV_2PI;

    const int wave = __builtin_amdgcn_readfirstlane((int)((blockIdx.x * blockDim.x + threadIdx.x) >> 6));
    const int nw   = (gridDim.x * blockDim.x) >> 6;
    float s1 = 0.f, s2 = 0.f;

    auto prefetch = [&](int v, int& sb, int& m, uint2& u) {
        sb = __builtin_amdgcn_readfirstlane(start[v]);
        int se = __builtin_amdgcn_readfirstlane(start[v + 1]);
        m = se - sb;
        int ms0 = min(m, 15);
        int row = min(rq, ms0);
        int ridx = sortedIdx[sb + row];        // padded; value unused when row==ms0
        const float* bp = (row == ms0) ? (feat + (size_t)v * CIN)
                                       : (xyz  + (size_t)ridx * CIN);
        float4 q = *(const float4*)(bp + cc * 4);
        u.x = bc_u(__builtin_amdgcn_cvt_pkrtz(q.x, q.y));
        u.y = bc_u(__builtin_amdgcn_cvt_pkrtz(q.z, q.w));
    };

    auto pointmath = [&](const uint2* buf, int j, v2f& acc) {
        uint4 a = ((const uint4*)buf)[j * 2 + 0];   // uniform -> broadcast
        uint4 b = ((const uint4*)buf)[j * 2 + 1];
        v2h xs[8] = {bc_h(a.x), bc_h(a.y), bc_h(a.z), bc_h(a.w),
                     bc_h(b.x), bc_h(b.y), bc_h(b.z), bc_h(b.w)};
        float dx = 0.f, dw = 0.f;
#pragma unroll
        for (int i = 0; i < 8; i++) {
            dx = __builtin_amdgcn_fdot2(xs[i], wpre2[i], dx, false);
            dw = __builtin_amdgcn_fdot2(xs[i], wcp2[i],  dw, false);
        }
        float p  = fmaf(AP, dx, BP);
        float r  = fmaf(dw, INV_2PI, CPr);
        float sv = __builtin_amdgcn_sinf(r);
        float cv = __builtin_amdgcn_cosf(r);
        acc += p * (v2f){sv, cv};
    };

    int v = wave;
    int sb = 0, m = 0;
    uint2* cur = bufA;
    uint2* nxt = bufB;
    if (v < V) {
        uint2 u; prefetch(v, sb, m, u);
        cur[wslot] = u;                        // ds_write_b64
    }

    while (v < V) {
        const int vn = v + nw;
        int sbn = 0, mn = 0; uint2 un = {};
        if (vn < V) prefetch(vn, sbn, mn, un); // VMEM in flight during compute

        const int ms0 = min(m, 15);
        v2f acc = (v2f){0.f, 0.f};

        for (int j = 0; j < ms0; j++) pointmath(cur, j, acc);

        // remainder rows for big voxels (m > 15), rare
        for (int base = 15; base < m; base += 16) {
            const int msr  = min(16, m - base);
            const int rowc = min(rq, msr - 1);
            int ridx = sortedIdx[sb + base + rowc];
            float4 q = *(const float4*)(xyz + (size_t)ridx * CIN + cc * 4);
            uint2 u;
            u.x = bc_u(__builtin_amdgcn_cvt_pkrtz(q.x, q.y));
            u.y = bc_u(__builtin_amdgcn_cvt_pkrtz(q.z, q.w));
            remb[wslot] = u;
            for (int j = 0; j < msr; j++) pointmath(remb, j, acc);
        }

        // center row (slot ms0): dx with wpre2, dw with sWcF2 (per-lane)
        {
            uint4 a = ((const uint4*)cur)[ms0 * 2 + 0];
            uint4 b = ((const uint4*)cur)[ms0 * 2 + 1];
            v2h xs[8] = {bc_h(a.x), bc_h(a.y), bc_h(a.z), bc_h(a.w),
                         bc_h(b.x), bc_h(b.y), bc_h(b.z), bc_h(b.w)};
            float dx = 0.f, dw = 0.f;
#pragma unroll
            for (int i = 0; i < 8; i++) {
                dx = __builtin_amdgcn_fdot2(xs[i], wpre2[i], dx, false);
                dw = __builtin_amdgcn_fdot2(xs[i], bc_h(sWcF2[i * 64 + lane]), dw, false);
            }
            float f  = fmaf(AF, dx, BF);
            float r  = fmaf(dw, INV_2PI, CFr);
            float sv = __builtin_amdgcn_sinf(r);
            float cv = __builtin_amdgcn_cosf(r);
            float cs = f * sv, ccn = f * cv;
            float fin = fmaf(acc.x + cs, cs, (acc.y + ccn) * ccn);
            outFinal[(size_t)v * 64 + lane] = fin;
            s1 += fin;
            s2 = fmaf(fin, fin, s2);
        }

        if (vn < V) nxt[wslot] = un;           // stage next voxel
        uint2* tmp = cur; cur = nxt; nxt = tmp;
        v = vn; sb = sbn; m = mn;
    }

    __shared__ float sh1[4][64], sh2[4][64];
    sh1[wid][lane] = s1; sh2[wid][lane] = s2;
    __syncthreads();
    if (threadIdx.x < 64) {
        float t1 = sh1[0][lane] + sh1[1][lane] + sh1[2][lane] + sh1[3][lane];
        float t2 = sh2[0][lane] + sh2[1][lane] + sh2[2][lane] + sh2[3][lane];
        float* row = statsPart + (size_t)(blockIdx.x & 63) * 128;
        atomicAdd(row + lane, t1);
        atomicAdd(row + 64 + lane, t2);
    }
}

// ---------------- normalize + relu, stats reduced per-block ----------------
__global__ __launch_bounds__(256) void norm_kernel(float* __restrict__ out,
                                                   const float* __restrict__ sp,
                                                   const float* __restrict__ gn,
                                                   const float* __restrict__ bnb,
                                                   int V, size_t n4)
{
    __shared__ float sNs[64], sNb[64];
    const int t = threadIdx.x;
    if (t < 64) {
        double u1 = 0.0, u2 = 0.0;
#pragma unroll 4
        for (int r = 0; r < 64; r++) {
            u1 += (double)sp[(size_t)r * 128 + t];
            u2 += (double)sp[(size_t)r * 128 + 64 + t];
        }
        double mean = u1 / (double)V;
        double var  = u2 / (double)V - mean * mean;
        double ns   = (double)gn[t] / sqrt(var + BN_EPS);
        sNs[t] = (float)ns;
        sNb[t] = (float)((double)bnb[t] - ns * mean);
    }
    __syncthreads();

    const float4* ns4 = (const float4*)sNs;
    const float4* nb4 = (const float4*)sNb;
    float4* o4 = (float4*)out;
    size_t i = (size_t)blockIdx.x * blockDim.x + threadIdx.x;
    size_t stride = (size_t)gridDim.x * blockDim.x;
    for (; i < n4; i += stride) {
        int g = (int)(i & 15);
        float4 sc = ns4[g], bi = nb4[g];
        float4 w = o4[i];
        w.x = fmaxf(0.f, fmaf(sc.x, w.x, bi.x));
        w.y = fmaxf(0.f, fmaf(sc.y, w.y, bi.y));
        w.z = fmaxf(0.f, fmaf(sc.z, w.z, bi.z));
        w.w = fmaxf(0.f, fmaf(sc.w, w.w, bi.w));
        o4[i] = w;
    }
}

extern "C" void kernel_launch(void* const* d_in, const int* in_sizes, int n_in,
                              void* d_out, int out_size, void* d_ws, size_t ws_size,
                              hipStream_t stream)
{
    const float* feat  = (const float*)d_in[0];
    const float* xyz   = (const float*)d_in[1];
    const int*   unq   = (const int*)d_in[2];
    const float* Wpre  = (const float*)d_in[3];
    const float* bpre  = (const float*)d_in[4];
    const float* gpre  = (const float*)d_in[5];
    const float* bepre = (const float*)d_in[6];
    const float* Wpos  = (const float*)d_in[7];
    const float* bpos  = (const float*)d_in[8];
    const float* gn    = (const float*)d_in[9];
    const float* bnb   = (const float*)d_in[10];

    const int V = in_sizes[0] / CIN;
    const int N = in_sizes[1] / CIN;
    const int nch = (V + CHUNK - 1) / CHUNK;

    char* ws = (char*)d_ws;
    size_t off = 0;
    auto alloc = [&](size_t bytes) { void* p = ws + off; off += (bytes + 255) & ~size_t(255); return p; };

    // zeroed region first: cnt, statsPart (one memset); cursor zeroed by scanC
    int*   cnt       = (int*)alloc((size_t)V * 4);
    float* statsPart = (float*)alloc(64 * 128 * 4);
    const size_t zeroBytes = off;

    int*   cursor    = (int*)alloc((size_t)V * 4);
    int*   start     = (int*)alloc((size_t)(V + 1) * 4);
    int*   chunkSum  = (int*)alloc(256 * 4);
    int*   sortedIdx = (int*)alloc((size_t)(N + 64) * 4);  // +64 pad for clamped gather

    float* partP = (float*)alloc((size_t)MB * NMOM * 4);
    float* partF = (float*)alloc((size_t)MB * NMOM * 4);
    float* prepP = (float*)alloc(P_SZ * 4);
    float* prepF = (float*)alloc(P_SZ * 4);

    hipMemsetAsync(d_ws, 0, zeroBytes, stream);

    moments2_kernel<<<2 * MB, 256, 0, stream>>>(xyz, N, feat, V, unq, cnt, partP, partF);
    prep_scanA<<<nch + 2, 256, 0, stream>>>(Wpre, bpre, gpre, bepre, Wpos, bpos,
                                            partP, partF, MB, N, V, prepP, prepF,
                                            cnt, V, chunkSum);
    scanC<<<nch, 64, 0, stream>>>(cnt, V, N, chunkSum, start, cursor);
    scatter_kernel<<<1024, 256, 0, stream>>>(unq, N, start, cursor, sortedIdx);
    fused_pass<<<2048, 256, 0, stream>>>(xyz, feat, sortedIdx, start, Wpre,
                                         prepP, prepF, (float*)d_out, statsPart, V);
    norm_kernel<<<512, 256, 0, stream>>>((float*)d_out, statsPart, gn, bnb, V,
                                         (size_t)out_size / 4);
}

// Round 18
// 187.654 us; speedup vs baseline: 1.3881x; 1.1848x over previous
//
#include <hip/hip_runtime.h>
#include <cstdint>
#include <cstddef>

constexpr int CIN  = 16;
constexpr int COUT = 64;
constexpr int NMOM = 16 + 136;          // 16 sums + 136 upper-tri products
constexpr double BN_EPS = 1e-3;

typedef float v2f __attribute__((ext_vector_type(2)));
typedef __fp16 v2h __attribute__((ext_vector_type(2)));   // matches cvt_pkrtz/fdot2 builtin type
constexpr float INV_2PI = 0.15915494309189535f;

// prep layout (floats): A[64], B[64], c[64], Wc[16*64]
constexpr int P_A = 0, P_B = 64, P_C = 128, P_WC = 192, P_SZ = 192 + CIN * COUT;

constexpr int CHUNK = 512;              // scan chunk
constexpr int MB = 256;                 // moments blocks per input; 1 partial row/block

__device__ __forceinline__ unsigned bc_u(v2h h) { return __builtin_bit_cast(unsigned, h); }
__device__ __forceinline__ v2h bc_h(unsigned u) { return __builtin_bit_cast(v2h, u); }

// ---------------- moments + histogram + slot record (one launch) -----------
// (256,2): acc[152]+staging ~185 VGPR fits under the 256-VGPR cap -> no
// spill, 2 waves/SIMD TLP. Histogram's atomicAdd return value IS the
// point's within-voxel slot -> record it so scatter needs no atomics.
__global__ __launch_bounds__(256, 2) void moments2_kernel(const float* __restrict__ xyz, int n1,
                                                       const float* __restrict__ feat, int n2,
                                                       const int* __restrict__ unq,
                                                       int* __restrict__ cnt,
                                                       int* __restrict__ slot32,
                                                       float* __restrict__ partP,
                                                       float* __restrict__ partF)
{
    const int bb  = blockIdx.x;
    const bool second = (bb >= MB);
    const float* x = second ? feat : xyz;
    const int    n = second ? n2 : n1;
    float* part    = second ? partF : partP;
    const int blk  = second ? bb - MB : bb;

    float acc[NMOM];
#pragma unroll
    for (int i = 0; i < NMOM; i++) acc[i] = 0.f;

    int tid = blk * 256 + threadIdx.x;
    int stride = MB * 256;
    for (int r = tid; r < n; r += stride) {
        const float4* xp = (const float4*)(x + (size_t)r * CIN);
        float4 a0 = xp[0], a1 = xp[1], a2 = xp[2], a3 = xp[3];
        if (!second) slot32[r] = atomicAdd(cnt + unq[r], 1);   // hist + slot
        float v[16] = {a0.x,a0.y,a0.z,a0.w, a1.x,a1.y,a1.z,a1.w,
                       a2.x,a2.y,a2.z,a2.w, a3.x,a3.y,a3.z,a3.w};
#pragma unroll
        for (int i = 0; i < 16; i++) acc[i] += v[i];
        int c = 16;
#pragma unroll
        for (int k = 0; k < 16; k++)
#pragma unroll
            for (int l = k; l < 16; l++) { acc[c] = fmaf(v[k], v[l], acc[c]); c++; }
    }

    const int lane = threadIdx.x & 63;
    const int wid  = threadIdx.x >> 6;
    float r0 = 0.f, r1 = 0.f, r2 = 0.f;
#pragma unroll
    for (int i = 0; i < NMOM; i++) {
        float s = acc[i];
#pragma unroll
        for (int off = 1; off < 64; off <<= 1) s += __shfl_xor(s, off, 64);
        if (i < 64)       { if (lane == i)       r0 = s; }
        else if (i < 128) { if (lane == i - 64)  r1 = s; }
        else              { if (lane == i - 128) r2 = s; }
    }

    __shared__ float red[4][NMOM];
    red[wid][lane] = r0;
    red[wid][64 + lane] = r1;
    if (lane < NMOM - 128) red[wid][128 + lane] = r2;
    __syncthreads();
    int t = threadIdx.x;
    if (t < NMOM) {
        float s = red[0][t] + red[1][t] + red[2][t] + red[3][t];
        part[(size_t)blk * NMOM + t] = s;
    }
}

// ---------------- prep (blocks 0,1) + scan_a (blocks 2..nch+1) -------------
__global__ __launch_bounds__(256) void prep_scanA(const float* __restrict__ Wpre, const float* __restrict__ bpre,
                            const float* __restrict__ gpre, const float* __restrict__ bepre,
                            const float* __restrict__ Wpos, const float* __restrict__ bpos,
                            const float* __restrict__ partP, const float* __restrict__ partF,
                            int nrows, int Np, int Vv,
                            float* __restrict__ prepP, float* __restrict__ prepF,
                            const int* __restrict__ cnt, int V,
                            int* __restrict__ chunkSum)
{
    const int t = threadIdx.x;   // 0..255
    const int lane = t & 63, wid = t >> 6;

    if (blockIdx.x >= 2) {
        // ---- scan_a: per-chunk sum of cnt ----
        const int b = blockIdx.x - 2;
        int base = b * CHUNK;
        int i0 = base + t * 2, i1 = i0 + 1;
        int s = ((i0 < V) ? cnt[i0] : 0) + ((i1 < V) ? cnt[i1] : 0);
        __shared__ int redc[4];
#pragma unroll
        for (int off = 1; off < 64; off <<= 1) s += __shfl_xor(s, off, 64);
        if (lane == 0) redc[wid] = s;
        __syncthreads();
        if (t == 0) chunkSum[b] = redc[0] + redc[1] + redc[2] + redc[3];
        return;
    }

    // ---- prep branch ----
    const int br = blockIdx.x;    // 0 or 1
    const float* part = br ? partF : partP;
    const double n    = br ? (double)Vv : (double)Np;
    const double inv_n = 1.0 / n;
    float* prep       = br ? prepF : prepP;

    __shared__ float sWpre[CIN * 64];    // 16x64
    __shared__ float sWpos[64 * 64];     // 64x64
    __shared__ double mom[NMOM];
    __shared__ double sS[64], sB[64];

    for (int i = t; i < CIN * 64; i += 256) sWpre[i] = Wpre[i];
    for (int i = t; i < 64 * 64; i += 256)  sWpos[i] = Wpos[i];

    if (t < NMOM) {
        double s0 = 0, s1 = 0, s2 = 0, s3 = 0, s4 = 0, s5 = 0, s6 = 0, s7 = 0;
        int r = 0;
        for (; r + 8 <= nrows; r += 8) {
            s0 += (double)part[(size_t)(r + 0) * NMOM + t];
            s1 += (double)part[(size_t)(r + 1) * NMOM + t];
            s2 += (double)part[(size_t)(r + 2) * NMOM + t];
            s3 += (double)part[(size_t)(r + 3) * NMOM + t];
            s4 += (double)part[(size_t)(r + 4) * NMOM + t];
            s5 += (double)part[(size_t)(r + 5) * NMOM + t];
            s6 += (double)part[(size_t)(r + 6) * NMOM + t];
            s7 += (double)part[(size_t)(r + 7) * NMOM + t];
        }
        for (; r < nrows; r++) s0 += (double)part[(size_t)r * NMOM + t];
        mom[t] = ((s0 + s1) + (s2 + s3)) + ((s4 + s5) + (s6 + s7));
    }
    __syncthreads();

    if (t < 64) {
        const int k = t;
        double mu[16];
#pragma unroll
        for (int i = 0; i < 16; i++) mu[i] = mom[i] * inv_n;
        double w[16];
#pragma unroll
        for (int i = 0; i < 16; i++) w[i] = (double)sWpre[i * 64 + k];

        double mk = (double)bpre[k];
#pragma unroll
        for (int i = 0; i < 16; i++) mk += mu[i] * w[i];

        double var = 0.0;
        int c = 16;
#pragma unroll
        for (int a = 0; a < 16; a++)
#pragma unroll
            for (int l = a; l < 16; l++) {
                double cov = mom[c] * inv_n - mu[a] * mu[l]; c++;
                var += (a == l ? 1.0 : 2.0) * w[a] * w[l] * cov;
            }

        double s_k = (double)gpre[k] / sqrt(var + BN_EPS);
        double B_k = (double)bepre[k] + s_k * ((double)bpre[k] - mk);
        sS[k] = s_k; sB[k] = B_k;
    }
    __syncthreads();

    if (t < 64) {
        const int k = t;
        double c0 = (double)bpos[k], c1 = 0.0;
        for (int j = 0; j < 64; j += 2) {
            c0 += sB[j]     * (double)sWpos[j * 64 + k];
            c1 += sB[j + 1] * (double)sWpos[(j + 1) * 64 + k];
        }
        prep[P_A + k] = (float)sS[k];
        prep[P_B + k] = (float)sB[k];
        prep[P_C + k] = (float)(c0 + c1);
    }

    {
        const int k  = t & 63;
        const int i0 = t >> 6;
        for (int i = i0; i < 16; i += 4) {
            double w0 = 0.0, w1 = 0.0;
            for (int j = 0; j < 64; j += 2) {
                w0 += (double)sWpre[i * 64 + j]     * sS[j]     * (double)sWpos[j * 64 + k];
                w1 += (double)sWpre[i * 64 + j + 1] * sS[j + 1] * (double)sWpos[(j + 1) * 64 + k];
            }
            prep[P_WC + i * 64 + k] = (float)(w0 + w1);
        }
    }
}

// ---------------- scanC: per-chunk scan + inline base ----------------------
__global__ __launch_bounds__(64) void scanC(const int* __restrict__ cnt, int V, int N,
                                            const int* __restrict__ chunkSum,
                                            int* __restrict__ start)
{
    const int b = blockIdx.x;
    const int lane = threadIdx.x;

    int pv = 0;
    for (int i = lane; i < b; i += 64) pv += chunkSum[i];
#pragma unroll
    for (int off = 1; off < 64; off <<= 1) pv += __shfl_xor(pv, off, 64);
    const int chunkBase = pv;

    const int base = b * CHUNK + lane * 8;
    int e[8];
    int run = 0;
#pragma unroll
    for (int j = 0; j < 8; j++) {
        int idx = base + j;
        int c = (idx < V) ? cnt[idx] : 0;
        e[j] = run;
        run += c;
    }
    int incl = run;
#pragma unroll
    for (int off = 1; off < 64; off <<= 1) {
        int vv = __shfl_up(incl, off, 64);
        if (lane >= off) incl += vv;
    }
    int excl = incl - run;
    int myBase = chunkBase + excl;
#pragma unroll
    for (int j = 0; j < 8; j++) {
        int idx = base + j;
        if (idx < V) start[idx] = myBase + e[j];
    }
    if (b == 0 && lane == 0) start[V] = N;
}

// ---------------- scatter: 4 range-partitioned sweeps, no atomics ----------
// Sweep k writes only voxels in [k*qsz,(k+1)*qsz): active sortedIdx region
// ~1 MB fits per-XCD L2 with no capacity evictions -> one writeback per
// dirtied line per XCD instead of repeated partial-line re-evictions.
__global__ __launch_bounds__(256) void scatter_kernel(const int* __restrict__ unq,
                                                      const int* __restrict__ slot32,
                                                      int N, int V,
                                                      const int* __restrict__ start,
                                                      int* __restrict__ sortedIdx)
{
    const int qsz = (V + 3) >> 2;
    const int t0 = blockIdx.x * blockDim.x + threadIdx.x;
    const int stride = gridDim.x * blockDim.x;
    for (int k = 0; k < 4; k++) {
        const int lo = k * qsz;
        const int hi = min(lo + qsz, V);
        for (int t = t0; t < N; t += stride) {
            int v = unq[t];
            if (v >= lo && v < hi)
                sortedIdx[start[v] + slot32[t]] = t;
        }
    }
}

// ---------------- fused voxel pass: f16 LDS rows + v_dot2_f32_f16 ----------
__global__ __launch_bounds__(256) void fused_pass(const float* __restrict__ xyz,
                                                  const float* __restrict__ feat,
                                                  const int* __restrict__ sortedIdx,
                                                  const int* __restrict__ start,
                                                  const float* __restrict__ Wpre,
                                                  const float* __restrict__ prepP,
                                                  const float* __restrict__ prepF,
                                                  float* __restrict__ outFinal,
                                                  float* __restrict__ statsPart, int V)
{
    const int lane = threadIdx.x & 63;
    const int wid  = threadIdx.x >> 6;
    const int rq   = lane >> 2;      // row slot 0..15
    const int cc   = lane & 3;       // quarter within row

    // per-wave LDS: 3 buffers x 16 rows x 16 halfs (512 B each)
    __shared__ uint2 ldsq[4][3][64];
    __shared__ unsigned sWcF2[8 * 64];      // center dw weights, half2-packed
    uint2* bufA = ldsq[wid][0];
    uint2* bufB = ldsq[wid][1];
    uint2* remb = ldsq[wid][2];
    const int wslot = rq * 4 + cc;

    for (int i = threadIdx.x; i < 8 * 64; i += 256) {
        int fi = i >> 6, ch = i & 63;
        sWcF2[i] = bc_u(__builtin_amdgcn_cvt_pkrtz(prepF[P_WC + (2 * fi) * 64 + ch],
                                                   prepF[P_WC + (2 * fi + 1) * 64 + ch]));
    }
    __syncthreads();

    v2h wpre2[8], wcp2[8];
#pragma unroll
    for (int i = 0; i < 8; i++) {
        wpre2[i] = __builtin_amdgcn_cvt_pkrtz(Wpre[(2 * i) * 64 + lane],
                                              Wpre[(2 * i + 1) * 64 + lane]);
        wcp2[i]  = __builtin_amdgcn_cvt_pkrtz(prepP[P_WC + (2 * i) * 64 + lane],
                                              prepP[P_WC + (2 * i + 1) * 64 + lane]);
    }

    const float AP = prepP[P_A + lane], BP = prepP[P_B + lane];
    const float CPr = prepP[P_C + lane] * INV_2PI;
    const float AF = prepF[P_A + lane], BF = prepF[P_B + lane];
    const float CFr = prepF[P_C + lane] * INV_2PI;

    const int wave = __builtin_amdgcn_readfirstlane((int)((blockIdx.x * blockDim.x + threadIdx.x) >> 6));
    const int nw   = (gridDim.x * blockDim.x) >> 6;
    float s1 = 0.f, s2 = 0.f;

    auto prefetch = [&](int v, int& sb, int& m, uint2& u) {
        sb = __builtin_amdgcn_readfirstlane(start[v]);
        int se = __builtin_amdgcn_readfirstlane(start[v + 1]);
        m = se - sb;
        int ms0 = min(m, 15);
        int row = min(rq, ms0);
        int ridx = sortedIdx[sb + row];        // padded; value unused when row==ms0
        const float* bp = (row == ms0) ? (feat + (size_t)v * CIN)
                                       : (xyz  + (size_t)ridx * CIN);
        float4 q = *(const float4*)(bp + cc * 4);
        u.x = bc_u(__builtin_amdgcn_cvt_pkrtz(q.x, q.y));
        u.y = bc_u(__builtin_amdgcn_cvt_pkrtz(q.z, q.w));
    };

    auto pointmath = [&](const uint2* buf, int j, v2f& acc) {
        uint4 a = ((const uint4*)buf)[j * 2 + 0];   // uniform -> broadcast
        uint4 b = ((const uint4*)buf)[j * 2 + 1];
        v2h xs[8] = {bc_h(a.x), bc_h(a.y), bc_h(a.z), bc_h(a.w),
                     bc_h(b.x), bc_h(b.y), bc_h(b.z), bc_h(b.w)};
        float dx = 0.f, dw = 0.f;
#pragma unroll
        for (int i = 0; i < 8; i++) {
            dx = __builtin_amdgcn_fdot2(xs[i], wpre2[i], dx, false);
            dw = __builtin_amdgcn_fdot2(xs[i], wcp2[i],  dw, false);
        }
        float p  = fmaf(AP, dx, BP);
        float r  = fmaf(dw, INV_2PI, CPr);
        float sv = __builtin_amdgcn_sinf(r);
        float cv = __builtin_amdgcn_cosf(r);
        acc += p * (v2f){sv, cv};
    };

    int v = wave;
    int sb = 0, m = 0;
    uint2* cur = bufA;
    uint2* nxt = bufB;
    if (v < V) {
        uint2 u; prefetch(v, sb, m, u);
        cur[wslot] = u;                        // ds_write_b64
    }

    while (v < V) {
        const int vn = v + nw;
        int sbn = 0, mn = 0; uint2 un = {};
        if (vn < V) prefetch(vn, sbn, mn, un); // VMEM in flight during compute

        const int ms0 = min(m, 15);
        v2f acc = (v2f){0.f, 0.f};

        for (int j = 0; j < ms0; j++) pointmath(cur, j, acc);

        // remainder rows for big voxels (m > 15), rare
        for (int base = 15; base < m; base += 16) {
            const int msr  = min(16, m - base);
            const int rowc = min(rq, msr - 1);
            int ridx = sortedIdx[sb + base + rowc];
            float4 q = *(const float4*)(xyz + (size_t)ridx * CIN + cc * 4);
            uint2 u;
            u.x = bc_u(__builtin_amdgcn_cvt_pkrtz(q.x, q.y));
            u.y = bc_u(__builtin_amdgcn_cvt_pkrtz(q.z, q.w));
            remb[wslot] = u;
            for (int j = 0; j < msr; j++) pointmath(remb, j, acc);
        }

        // center row (slot ms0): dx with wpre2, dw with sWcF2 (per-lane)
        {
            uint4 a = ((const uint4*)cur)[ms0 * 2 + 0];
            uint4 b = ((const uint4*)cur)[ms0 * 2 + 1];
            v2h xs[8] = {bc_h(a.x), bc_h(a.y), bc_h(a.z), bc_h(a.w),
                         bc_h(b.x), bc_h(b.y), bc_h(b.z), bc_h(b.w)};
            float dx = 0.f, dw = 0.f;
#pragma unroll
            for (int i = 0; i < 8; i++) {
                dx = __builtin_amdgcn_fdot2(xs[i], wpre2[i], dx, false);
                dw = __builtin_amdgcn_fdot2(xs[i], bc_h(sWcF2[i * 64 + lane]), dw, false);
            }
            float f  = fmaf(AF, dx, BF);
            float r  = fmaf(dw, INV_2PI, CFr);
            float sv = __builtin_amdgcn_sinf(r);
            float cv = __builtin_amdgcn_cosf(r);
            float cs = f * sv, ccn = f * cv;
            float fin = fmaf(acc.x + cs, cs, (acc.y + ccn) * ccn);
            outFinal[(size_t)v * 64 + lane] = fin;
            s1 += fin;
            s2 = fmaf(fin, fin, s2);
        }

        if (vn < V) nxt[wslot] = un;           // stage next voxel
        uint2* tmp = cur; cur = nxt; nxt = tmp;
        v = vn; sb = sbn; m = mn;
    }

    __shared__ float sh1[4][64], sh2[4][64];
    sh1[wid][lane] = s1; sh2[wid][lane] = s2;
    __syncthreads();
    if (threadIdx.x < 64) {
        float t1 = sh1[0][lane] + sh1[1][lane] + sh1[2][lane] + sh1[3][lane];
        float t2 = sh2[0][lane] + sh2[1][lane] + sh2[2][lane] + sh2[3][lane];
        float* row = statsPart + (size_t)(blockIdx.x & 63) * 128;
        atomicAdd(row + lane, t1);
        atomicAdd(row + 64 + lane, t2);
    }
}

// ---------------- normalize + relu, stats reduced per-block ----------------
__global__ __launch_bounds__(256) void norm_kernel(float* __restrict__ out,
                                                   const float* __restrict__ sp,
                                                   const float* __restrict__ gn,
                                                   const float* __restrict__ bnb,
                                                   int V, size_t n4)
{
    __shared__ float sNs[64], sNb[64];
    const int t = threadIdx.x;
    if (t < 64) {
        double u1 = 0.0, u2 = 0.0;
#pragma unroll 4
        for (int r = 0; r < 64; r++) {
            u1 += (double)sp[(size_t)r * 128 + t];
            u2 += (double)sp[(size_t)r * 128 + 64 + t];
        }
        double mean = u1 / (double)V;
        double var  = u2 / (double)V - mean * mean;
        double ns   = (double)gn[t] / sqrt(var + BN_EPS);
        sNs[t] = (float)ns;
        sNb[t] = (float)((double)bnb[t] - ns * mean);
    }
    __syncthreads();

    const float4* ns4 = (const float4*)sNs;
    const float4* nb4 = (const float4*)sNb;
    float4* o4 = (float4*)out;
    size_t i = (size_t)blockIdx.x * blockDim.x + threadIdx.x;
    size_t stride = (size_t)gridDim.x * blockDim.x;
    for (; i < n4; i += stride) {
        int g = (int)(i & 15);
        float4 sc = ns4[g], bi = nb4[g];
        float4 w = o4[i];
        w.x = fmaxf(0.f, fmaf(sc.x, w.x, bi.x));
        w.y = fmaxf(0.f, fmaf(sc.y, w.y, bi.y));
        w.z = fmaxf(0.f, fmaf(sc.z, w.z, bi.z));
        w.w = fmaxf(0.f, fmaf(sc.w, w.w, bi.w));
        o4[i] = w;
    }
}

extern "C" void kernel_launch(void* const* d_in, const int* in_sizes, int n_in,
                              void* d_out, int out_size, void* d_ws, size_t ws_size,
                              hipStream_t stream)
{
    const float* feat  = (const float*)d_in[0];
    const float* xyz   = (const float*)d_in[1];
    const int*   unq   = (const int*)d_in[2];
    const float* Wpre  = (const float*)d_in[3];
    const float* bpre  = (const float*)d_in[4];
    const float* gpre  = (const float*)d_in[5];
    const float* bepre = (const float*)d_in[6];
    const float* Wpos  = (const float*)d_in[7];
    const float* bpos  = (const float*)d_in[8];
    const float* gn    = (const float*)d_in[9];
    const float* bnb   = (const float*)d_in[10];

    const int V = in_sizes[0] / CIN;
    const int N = in_sizes[1] / CIN;
    const int nch = (V + CHUNK - 1) / CHUNK;

    char* ws = (char*)d_ws;
    size_t off = 0;
    auto alloc = [&](size_t bytes) { void* p = ws + off; off += (bytes + 255) & ~size_t(255); return p; };

    // zeroed region first: cnt, statsPart (one memset)
    int*   cnt       = (int*)alloc((size_t)V * 4);
    float* statsPart = (float*)alloc(64 * 128 * 4);
    const size_t zeroBytes = off;

    int*   slot32    = (int*)alloc((size_t)N * 4);
    int*   start     = (int*)alloc((size_t)(V + 1) * 4);
    int*   chunkSum  = (int*)alloc(256 * 4);
    int*   sortedIdx = (int*)alloc((size_t)(N + 64) * 4);  // +64 pad for clamped gather

    float* partP = (float*)alloc((size_t)MB * NMOM * 4);
    float* partF = (float*)alloc((size_t)MB * NMOM * 4);
    float* prepP = (float*)alloc(P_SZ * 4);
    float* prepF = (float*)alloc(P_SZ * 4);

    hipMemsetAsync(d_ws, 0, zeroBytes, stream);

    moments2_kernel<<<2 * MB, 256, 0, stream>>>(xyz, N, feat, V, unq, cnt, slot32, partP, partF);
    prep_scanA<<<nch + 2, 256, 0, stream>>>(Wpre, bpre, gpre, bepre, Wpos, bpos,
                                            partP, partF, MB, N, V, prepP, prepF,
                                            cnt, V, chunkSum);
    scanC<<<nch, 64, 0, stream>>>(cnt, V, N, chunkSum, start);
    scatter_kernel<<<1024, 256, 0, stream>>>(unq, slot32, N, V, start, sortedIdx);
    fused_pass<<<2048, 256, 0, stream>>>(xyz, feat, sortedIdx, start, Wpre,
                                         prepP, prepF, (float*)d_out, statsPart, V);
    norm_kernel<<<512, 256, 0, stream>>>((float*)d_out, statsPart, gn, bnb, V,
                                         (size_t)out_size / 4);
}